// Round 21
// baseline (793.191 us; speedup 1.0000x reference)
//
#include <hip/hip_runtime.h>
#include <stdint.h>

#define D_MODEL 1024
#define NHEAD   16
#define DK      64
#define SS      2048
#define BB      4

typedef short bf16x8 __attribute__((ext_vector_type(8)));
typedef _Float16 f16x8 __attribute__((ext_vector_type(8)));
typedef unsigned short u16x8 __attribute__((ext_vector_type(8)));
typedef unsigned short u16x4 __attribute__((ext_vector_type(4)));
typedef float f32x4  __attribute__((ext_vector_type(4)));

#if __has_builtin(__builtin_amdgcn_exp2f)
#define EXP2(x) __builtin_amdgcn_exp2f(x)
#else
#define EXP2(x) __expf((x) * 0.6931471805599453f)
#endif

#define QSCALE_F 0.1803368801111204f   // 0.125 * log2(e)

__device__ inline unsigned short f2bf(float x) {
    unsigned u = __float_as_uint(x);
    return (unsigned short)((u + 0x7fff + ((u >> 16) & 1)) >> 16);
}
__device__ inline float bf2f(unsigned short h) {
    return __uint_as_float(((unsigned)h) << 16);
}
__device__ inline unsigned short f2h(float x) {
    _Float16 h = (_Float16)x;           // v_cvt_f16_f32 (RNE)
    return __builtin_bit_cast(unsigned short, h);
}

__device__ inline void gll16(const void* g, void* l) {
    __builtin_amdgcn_global_load_lds(
        (const __attribute__((address_space(1))) unsigned int*)(g),
        (__attribute__((address_space(3))) unsigned int*)(l),
        16, 0, 0);
}

// ---------------------------------------------------------------------------
// Pre-split: fp32 row-major [R][1024] -> single fp16, tiled-swizzled.
// ---------------------------------------------------------------------------
struct SplitJob { const float* src; unsigned short* dst; int nchunks; };
struct SplitJobs8 { SplitJob j[8]; };

__global__ __launch_bounds__(256) void presplit(SplitJobs8 jobs) {
    const SplitJob J = jobs.j[blockIdx.y];
    int g = blockIdx.x * 256 + threadIdx.x;
    if (g >= J.nchunks) return;
    int tile = g >> 9;
    int w    = g & 511;
    int r    = w >> 2;
    int cc   = w & 3;
    int mt   = tile >> 5;
    int kt   = tile & 31;
    int m    = mt * 128 + r;
    int k0   = kt * 32 + cc * 8;

    const float* s = J.src + (size_t)m * 1024 + k0;
    float4 f0 = *(const float4*)s;
    float4 f1 = *(const float4*)(s + 4);
    float vals[8] = {f0.x, f0.y, f0.z, f0.w, f1.x, f1.y, f1.z, f1.w};
    u16x8 h8;
#pragma unroll
    for (int i = 0; i < 8; ++i) h8[i] = f2h(vals[i]);
    int slot = cc ^ (r & 3) ^ ((r >> 2) & 3);
    size_t doff = (size_t)tile * 4096 + r * 32 + slot * 8;
    *(u16x8*)(J.dst + doff) = h8;
}

// ---------------------------------------------------------------------------
// Single-pass fp16 MFMA GEMM: C = A * W^T + bias.  (validated R17-R20)
// MODE 0: fp32 [M,N]
// MODE 2: fp16 [B,H,S,DK]                      (K for attention)
// MODE 3: fp16 TRANSPOSED [(b*H+h)][d][S]      (V, fused transpose)
// MODE 4: fp16 [B,H,S,DK], scaled by QSCALE    (Q, pre-scaled for softmax)
// ---------------------------------------------------------------------------
template <int MODE>
__global__ __launch_bounds__(256) void gemm_f16(const unsigned short* __restrict__ A,
                                                const unsigned short* __restrict__ B,
                                                const float* __restrict__ bias,
                                                float* __restrict__ C,
                                                unsigned short* __restrict__ C16) {
    __shared__ unsigned short As[4096], Bs[4096];

    const int tid  = threadIdx.x;
    const int lane = tid & 63;
    const int wid  = tid >> 6;
    const int bx   = blockIdx.x;
    const int by   = blockIdx.y;
    const int wr   = wid >> 1;
    const int wc   = wid & 1;
    const int fr   = lane & 15;
    const int fg   = lane >> 4;
    const int chunk = fg ^ (fr & 3) ^ ((fr >> 2) & 3);

    f32x4 acc[4][4] = {};

    const size_t aT = (size_t)by * 32;
    const size_t bT = (size_t)bx * 32;
    const int soff  = wid * 2048 + lane * 16;

    for (int kt = 0; kt < 32; ++kt) {
        const char* at = (const char*)A + ((aT + kt) << 13);
        const char* bt = (const char*)B + ((bT + kt) << 13);
        gll16(at + soff,        (char*)As + soff);
        gll16(at + soff + 1024, (char*)As + soff + 1024);
        gll16(bt + soff,        (char*)Bs + soff);
        gll16(bt + soff + 1024, (char*)Bs + soff + 1024);
        __syncthreads();

        f16x8 ah[4], bh[4];
#pragma unroll
        for (int mi = 0; mi < 4; ++mi) {
            int ro = (wr * 64 + mi * 16 + fr) * 64 + chunk * 16;
            ah[mi] = *(const f16x8*)((const char*)As + ro);
        }
#pragma unroll
        for (int ni = 0; ni < 4; ++ni) {
            int ro = (wc * 64 + ni * 16 + fr) * 64 + chunk * 16;
            bh[ni] = *(const f16x8*)((const char*)Bs + ro);
        }
#pragma unroll
        for (int mi = 0; mi < 4; ++mi)
#pragma unroll
            for (int ni = 0; ni < 4; ++ni)
                acc[mi][ni] = __builtin_amdgcn_mfma_f32_16x16x32_f16(ah[mi], bh[ni], acc[mi][ni], 0, 0, 0);
        __syncthreads();
    }

#pragma unroll
    for (int ni = 0; ni < 4; ++ni) {
        int col = bx * 128 + wc * 64 + ni * 16 + fr;
        float bb = bias[col];
#pragma unroll
        for (int mi = 0; mi < 4; ++mi) {
            if (MODE == 3) {
                int row0 = by * 128 + wr * 64 + mi * 16 + fg * 4;
                int bq = row0 >> 11, s0 = row0 & (SS - 1);
                int h = col >> 6, d = col & 63;
                u16x4 h4;
#pragma unroll
                for (int r2 = 0; r2 < 4; ++r2)
                    h4[r2] = f2h(acc[mi][ni][r2] + bb);
                size_t obase = (((size_t)(bq * NHEAD + h) * 64 + d) * SS + s0);
                *(u16x4*)&C16[obase] = h4;
            } else {
#pragma unroll
                for (int r2 = 0; r2 < 4; ++r2) {
                    int row = by * 128 + wr * 64 + mi * 16 + fg * 4 + r2;
                    float cv = acc[mi][ni][r2] + bb;
                    if (MODE == 0) {
                        C[(size_t)row * D_MODEL + col] = cv;
                    } else {
                        int bq = row >> 11, s = row & (SS - 1), h = col >> 6, d = col & 63;
                        size_t base = (((size_t)(bq * NHEAD + h) * SS + s) << 6) + d;
                        if (MODE == 2) C16[base] = f2h(cv);
                        else           C16[base] = f2h(cv * QSCALE_F);   // MODE 4
                    }
                }
            }
        }
    }
}

// ---------------------------------------------------------------------------
// fp16 flash attention v5: R20 (KVBLK=128, fp16 Pbuf, fixed-max softmax) +
// __launch_bounds__(512, 8): caps VGPR at 64 so 4 blocks/CU fit -> capacity
// 1024 = grid -> ONE residency round. (R20's VGPR crept to 68 -> 7 waves/SIMD
// -> 3 blocks/CU -> 768+256 two-round schedule, occupancy 22%.)
// ---------------------------------------------------------------------------
__global__ __launch_bounds__(512, 8) void attn_f16(const unsigned short* __restrict__ Q16,
                                                   const unsigned short* __restrict__ K16,
                                                   const unsigned short* __restrict__ VT16,
                                                   const int* __restrict__ mask,
                                                   unsigned short* __restrict__ Ac) {
    __shared__ unsigned short Ks[8192];   // [128 key][64 d], 8-slot swz per row
    __shared__ unsigned short Vs[8192];   // [64 d][128 key], 16-slot swz per row
    __shared__ unsigned short Pb[8][16 * 32];   // fp16 P, chunk-XOR swizzled

    const int tid  = threadIdx.x;
    const int lane = tid & 63;
    const int wid  = tid >> 6;

    const int bid = blockIdx.x;
    const int swz = (bid & 7) * 128 + (bid >> 3);
    const int qt  = swz & 15;
    const int bh  = swz >> 4;
    const int b   = bh >> 4;
    const int h   = bh & 15;

    const int q0  = qt * 128;
    const int wq0 = wid * 16;

    const int fr = lane & 15;
    const int fg = lane >> 4;

    const unsigned short* qb   = Q16 + ((size_t)bh * SS + q0 + wq0) * DK;
    const unsigned short* kb16 = K16 + (size_t)bh * SS * DK;
    const unsigned short* vb16 = VT16 + (size_t)bh * DK * SS;
    const int* mrow = mask + b * SS;

    // Q fragments: direct fp16 loads (already scaled)
    f16x8 qf[2];
#pragma unroll
    for (int kb = 0; kb < 2; ++kb)
        qf[kb] = *(const f16x8*)&qb[(size_t)fr * DK + kb * 32 + fg * 8];

    f16x8 ONES16;
#pragma unroll
    for (int i = 0; i < 8; ++i) ONES16[i] = (_Float16)1.0f;

    f32x4 O[4] = {};
    f32x4 Lacc = {};

    // staging: 1024 chunks per array, 2 per thread per array
    const int c0 = tid, c1 = tid + 512;
    const int k0r = c0 >> 3, k0s = c0 & 7;
    const int k1r = c1 >> 3, k1s = c1 & 7;
    const int k0d = k0r * 64 + ((k0s ^ (k0r & 7)) << 3);
    const int k1d = k1r * 64 + ((k1s ^ (k1r & 7)) << 3);
    const int k0g = k0r * 64 + k0s * 8;      // + kv0*64
    const int k1g = k1r * 64 + k1s * 8;
    const int v0r = c0 >> 4, v0s = c0 & 15;
    const int v1r = c1 >> 4, v1s = c1 & 15;
    const int v0d = v0r * 128 + ((v0s ^ (v0r & 15)) << 3);
    const int v1d = v1r * 128 + ((v1s ^ (v1r & 15)) << 3);
    const int v0g = v0r * SS + v0s * 8;      // + kv0
    const int v1g = v1r * SS + v1s * 8;

    const int sl0 = ((0 + fg) ^ (fr & 7)) * 8;
    const int sl1 = ((4 + fg) ^ (fr & 7)) * 8;

    unsigned short* pw16 = Pb[wid];
    // P read: single 16B chunk, logical chunk fg, swizzled by row(fr)&3
    const int prd_off = fr * 32 + ((fg ^ (fr & 3)) << 3);

    // prologue: stage tile 0 into regs
    u16x8 rK0 = *(const u16x8*)&kb16[k0g];
    u16x8 rK1 = *(const u16x8*)&kb16[k1g];
    u16x8 rV0 = *(const u16x8*)&vb16[v0g];
    u16x8 rV1 = *(const u16x8*)&vb16[v1g];

    for (int t = 0; t < SS / 128; ++t) {
        const int kv0 = t * 128;

        __syncthreads();   // previous tile's LDS reads complete
        *(u16x8*)&Ks[k0d] = rK0;
        *(u16x8*)&Ks[k1d] = rK1;
        *(u16x8*)&Vs[v0d] = rV0;
        *(u16x8*)&Vs[v1d] = rV1;
        __syncthreads();   // tile t visible

        if (t + 1 < SS / 128) {
            const int kn = kv0 + 128;
            rK0 = *(const u16x8*)&kb16[(size_t)kn * 64 + k0g];
            rK1 = *(const u16x8*)&kb16[(size_t)kn * 64 + k1g];
            rV0 = *(const u16x8*)&vb16[v0g + kn];
            rV1 = *(const u16x8*)&vb16[v1g + kn];
        }

        // two 64-key sub-tiles
#pragma unroll
        for (int sub = 0; sub < 2; ++sub) {
            const int kvs = kv0 + sub * 64;

            int mv[4];
#pragma unroll
            for (int kyb = 0; kyb < 4; ++kyb) mv[kyb] = mrow[kvs + kyb * 16 + fr];
            const int allm = mv[0] & mv[1] & mv[2] & mv[3];
            const bool nomask = __all(allm != 0);

            // --- QK^T: 8 MFMA
            f32x4 acc[4] = {};
            __builtin_amdgcn_s_setprio(1);
#pragma unroll
            for (int kyb = 0; kyb < 4; ++kyb) {
                const int rb = (sub * 64 + kyb * 16 + fr) * 64;
                f16x8 k0 = *(const f16x8*)&Ks[rb + sl0];
                f16x8 k1 = *(const f16x8*)&Ks[rb + sl1];
                acc[kyb] = __builtin_amdgcn_mfma_f32_16x16x32_f16(qf[0], k0, acc[kyb], 0, 0, 0);
                acc[kyb] = __builtin_amdgcn_mfma_f32_16x16x32_f16(qf[1], k1, acc[kyb], 0, 0, 0);
            }
            __builtin_amdgcn_s_setprio(0);

            // --- fixed-max softmax: p = exp2(score)  (mask -> 0)
            float p[4][4];
            if (nomask) {
#pragma unroll
                for (int kyb = 0; kyb < 4; ++kyb)
#pragma unroll
                    for (int r = 0; r < 4; ++r)
                        p[kyb][r] = EXP2(acc[kyb][r]);
            } else {
#pragma unroll
                for (int kyb = 0; kyb < 4; ++kyb)
#pragma unroll
                    for (int r = 0; r < 4; ++r)
                        p[kyb][r] = mv[kyb] ? EXP2(acc[kyb][r]) : 0.f;
            }

            // --- two PV half-phases (Pbuf holds 32 keys, fp16)
#pragma unroll
            for (int ph2 = 0; ph2 < 2; ++ph2) {
#pragma unroll
                for (int kyb2 = 0; kyb2 < 2; ++kyb2)
#pragma unroll
                    for (int r = 0; r < 4; ++r) {
                        int row = fg * 4 + r;
                        int co  = kyb2 * 16 + fr;
                        int ch  = (co >> 3) ^ (row & 3);
                        pw16[row * 32 + ch * 8 + (co & 7)] = f2h(p[ph2 * 2 + kyb2][r]);
                    }

                asm volatile("s_waitcnt lgkmcnt(0)" ::: "memory");
                __builtin_amdgcn_sched_barrier(0);

                f16x8 pf = *(const f16x8*)&pw16[prd_off];

                // V logical key-chunk: sub*8 + ph2*4 + fg, swizzled by row&15=fr
                const int vsl = (((sub * 8 + ph2 * 4 + fg) ^ (fr & 15)) << 3);
                __builtin_amdgcn_s_setprio(1);
                Lacc = __builtin_amdgcn_mfma_f32_16x16x32_f16(pf, ONES16, Lacc, 0, 0, 0);
#pragma unroll
                for (int db = 0; db < 4; ++db) {
                    const int rb = (db * 16 + fr) * 128 + vsl;
                    f16x8 vf = *(const f16x8*)&Vs[rb];
                    O[db] = __builtin_amdgcn_mfma_f32_16x16x32_f16(pf, vf, O[db], 0, 0, 0);
                }
                __builtin_amdgcn_s_setprio(0);

                // WAR fence: Pbuf reads retired before next writes
                asm volatile("s_waitcnt lgkmcnt(0)" ::: "memory");
                __builtin_amdgcn_sched_barrier(0);
            }
        }
    }

    // --- epilogue: fp16 tiled-swizzled ctx store
#pragma unroll
    for (int r = 0; r < 4; ++r) {
        float inv = 1.0f / Lacc[r];
        int m  = b * SS + q0 + wq0 + fg * 4 + r;
        int rt = m & 127;
        int mt = m >> 7;
        int rx = (rt & 3) ^ ((rt >> 2) & 3);
#pragma unroll
        for (int db = 0; db < 4; ++db) {
            float val = O[db][r] * inv;
            int kcol = h * 64 + db * 16 + fr;
            int tile = mt * 32 + (kcol >> 5);
            int slot = (((kcol >> 3) & 3)) ^ rx;
            size_t doff = (size_t)tile * 4096 + rt * 32 + slot * 8 + (kcol & 7);
            Ac[doff] = f2h(val);
        }
    }
}

// ---------------------------------------------------------------------------
// fp32 GEMM + old attention (fallback path, unchanged/validated)
// ---------------------------------------------------------------------------
template <int MODE>
__global__ __launch_bounds__(256) void gemm_xwT(const float* __restrict__ A,
                                                const float* __restrict__ W,
                                                const float* __restrict__ bias,
                                                float* __restrict__ C,
                                                unsigned short* __restrict__ Chi,
                                                unsigned short* __restrict__ Clo,
                                                int M, int N, int K) {
    __shared__ float As[8][132];
    __shared__ float Bs[8][132];

    const int tid = threadIdx.x;
    const int tx  = tid & 15;
    const int ty  = tid >> 4;
    const int m0  = blockIdx.y * 128;
    const int n0  = blockIdx.x * 128;

    const int lr = tid >> 1;
    const int lk = (tid & 1) * 4;

    float acc[8][8];
#pragma unroll
    for (int i = 0; i < 8; ++i)
#pragma unroll
        for (int j = 0; j < 8; ++j) acc[i][j] = 0.f;

    for (int kt = 0; kt < K; kt += 8) {
        float4 av = *(const float4*)&A[(size_t)(m0 + lr) * K + kt + lk];
        float4 wv = *(const float4*)&W[(size_t)(n0 + lr) * K + kt + lk];
        __syncthreads();
        As[lk + 0][lr] = av.x; As[lk + 1][lr] = av.y;
        As[lk + 2][lr] = av.z; As[lk + 3][lr] = av.w;
        Bs[lk + 0][lr] = wv.x; Bs[lk + 1][lr] = wv.y;
        Bs[lk + 2][lr] = wv.z; Bs[lk + 3][lr] = wv.w;
        __syncthreads();
#pragma unroll
        for (int k = 0; k < 8; ++k) {
            float4 a0 = *(const float4*)&As[k][ty * 8];
            float4 a1 = *(const float4*)&As[k][ty * 8 + 4];
            float4 b0 = *(const float4*)&Bs[k][tx * 8];
            float4 b1 = *(const float4*)&Bs[k][tx * 8 + 4];
            float a[8] = {a0.x, a0.y, a0.z, a0.w, a1.x, a1.y, a1.z, a1.w};
            float b[8] = {b0.x, b0.y, b0.z, b0.w, b1.x, b1.y, b1.z, b1.w};
#pragma unroll
            for (int i = 0; i < 8; ++i)
#pragma unroll
                for (int j = 0; j < 8; ++j) acc[i][j] += a[i] * b[j];
        }
    }

    float bb[8];
#pragma unroll
    for (int j = 0; j < 8; ++j) bb[j] = bias[n0 + tx * 8 + j];

#pragma unroll
    for (int i = 0; i < 8; ++i) {
        int m = m0 + ty * 8 + i;
        int n = n0 + tx * 8;
        float cv[8];
#pragma unroll
        for (int j = 0; j < 8; ++j) cv[j] = acc[i][j] + bb[j];

        if (MODE == 0) {
            float* dst = &C[(size_t)m * N + n];
            *(float4*)&dst[0] = {cv[0], cv[1], cv[2], cv[3]};
            *(float4*)&dst[4] = {cv[4], cv[5], cv[6], cv[7]};
        } else {
            int bq = m >> 11;
            int s  = m & (SS - 1);
            int h  = n >> 6;
            int d  = n & 63;
            size_t base = (((size_t)(bq * NHEAD + h) * SS + s) << 6) + d;
            if (MODE == 1) {
                float* dst = &C[base];
                *(float4*)&dst[0] = {cv[0], cv[1], cv[2], cv[3]};
                *(float4*)&dst[4] = {cv[4], cv[5], cv[6], cv[7]};
            } else {
                u16x8 h8, l8;
#pragma unroll
                for (int j = 0; j < 8; ++j) {
                    unsigned short hv = f2bf(cv[j]);
                    h8[j] = hv;
                    l8[j] = f2bf(cv[j] - bf2f(hv));
                }
                *(u16x8*)&Chi[base] = h8;
                *(u16x8*)&Clo[base] = l8;
            }
        }
    }
}

__global__ __launch_bounds__(256) void attn_mfma(const float* __restrict__ Qp,
                                                 const unsigned short* __restrict__ Khig,
                                                 const unsigned short* __restrict__ Klog,
                                                 const unsigned short* __restrict__ Vhig,
                                                 const unsigned short* __restrict__ Vlog,
                                                 const int* __restrict__ mask,
                                                 float* __restrict__ ctx) {
    __shared__ short Khi[32 * 72], Klo[32 * 72];
    __shared__ short Vhi[64 * 40], Vlo[64 * 40];
    __shared__ float Pbuf[4][16 * 36];
    __shared__ int   msk[32];

    const int tid  = threadIdx.x;
    const int lane = tid & 63;
    const int wid  = tid >> 6;

    const int bid = blockIdx.x;
    const int swz = (bid & 7) * 256 + (bid >> 3);
    const int qt  = swz & 31;
    const int bh  = swz >> 5;
    const int b   = bh >> 4;
    const int h   = bh & 15;

    const int q0  = qt * 64;
    const int wq0 = wid * 16;

    const int fr = lane & 15;
    const int fg = lane >> 4;

    const float* qbase = Qp + ((size_t)bh * SS + q0 + wq0) * DK;
    const unsigned short* khbase = Khig + (size_t)bh * SS * DK;
    const unsigned short* klbase = Klog + (size_t)bh * SS * DK;
    const unsigned short* vhbase = Vhig + (size_t)bh * SS * DK;
    const unsigned short* vlbase = Vlog + (size_t)bh * SS * DK;
    const int* mrow = mask + b * SS;

    bf16x8 qh[2], ql[2];
#pragma unroll
    for (int kb = 0; kb < 2; ++kb) {
        const float* p = qbase + (size_t)fr * DK + kb * 32 + fg * 8;
        float4 a  = *(const float4*)p;
        float4 b4 = *(const float4*)(p + 4);
        float vals[8] = {a.x, a.y, a.z, a.w, b4.x, b4.y, b4.z, b4.w};
#pragma unroll
        for (int i = 0; i < 8; ++i) {
            float s = vals[i] * 0.125f;
            unsigned short hi = f2bf(s);
            qh[kb][i] = (short)hi;
            ql[kb][i] = (short)f2bf(s - bf2f(hi));
        }
    }

    f32x4 O[4] = {};
    float m_run[4], l_run[4];
#pragma unroll
    for (int r = 0; r < 4; ++r) { m_run[r] = -3.0e38f; l_run[r] = 0.f; }

    const int sk_k = tid >> 3;
    const int sk_d = (tid & 7) * 8;
    const int sv_d = tid & 63;
    const int sv_k = (tid >> 6) * 8;

    for (int t = 0; t < SS / 32; ++t) {
        const int kv0 = t * 32;

        size_t koff = (size_t)(kv0 + sk_k) * DK + sk_d;
        u16x8 kh8 = *(const u16x8*)&khbase[koff];
        u16x8 kl8 = *(const u16x8*)&klbase[koff];
        unsigned short vh[8], vl[8];
#pragma unroll
        for (int j = 0; j < 8; ++j) {
            size_t voff = (size_t)(kv0 + sv_k + j) * DK + sv_d;
            vh[j] = vhbase[voff];
            vl[j] = vlbase[voff];
        }
        int mval = (tid < 32) ? mrow[kv0 + tid] : 0;

        __syncthreads();
        *(u16x8*)&Khi[sk_k * 72 + sk_d] = kh8;
        *(u16x8*)&Klo[sk_k * 72 + sk_d] = kl8;
        {
            u16x8 h8, l8;
#pragma unroll
            for (int j = 0; j < 8; ++j) { h8[j] = vh[j]; l8[j] = vl[j]; }
            *(u16x8*)&Vhi[sv_d * 40 + sv_k] = h8;
            *(u16x8*)&Vlo[sv_d * 40 + sv_k] = l8;
        }
        if (tid < 32) msk[tid] = mval;
        __syncthreads();

        f32x4 acc[2] = {};
#pragma unroll
        for (int kyb = 0; kyb < 2; ++kyb) {
#pragma unroll
            for (int kb = 0; kb < 2; ++kb) {
                int idx = (kyb * 16 + fr) * 72 + kb * 32 + fg * 8;
                bf16x8 kh = *(const bf16x8*)&Khi[idx];
                bf16x8 kl = *(const bf16x8*)&Klo[idx];
                acc[kyb] = __builtin_amdgcn_mfma_f32_16x16x32_bf16(qh[kb], kh, acc[kyb], 0, 0, 0);
                acc[kyb] = __builtin_amdgcn_mfma_f32_16x16x32_bf16(qh[kb], kl, acc[kyb], 0, 0, 0);
                acc[kyb] = __builtin_amdgcn_mfma_f32_16x16x32_bf16(ql[kb], kh, acc[kyb], 0, 0, 0);
            }
        }

        float sc[2][4];
#pragma unroll
        for (int kyb = 0; kyb < 2; ++kyb) {
            int mv = msk[kyb * 16 + fr];
#pragma unroll
            for (int r = 0; r < 4; ++r)
                sc[kyb][r] = mv ? acc[kyb][r] : -1.0e9f;
        }
        float scale[4], p[2][4];
#pragma unroll
        for (int r = 0; r < 4; ++r) {
            float v = fmaxf(sc[0][r], sc[1][r]);
            v = fmaxf(v, __shfl_xor(v, 1));
            v = fmaxf(v, __shfl_xor(v, 2));
            v = fmaxf(v, __shfl_xor(v, 4));
            v = fmaxf(v, __shfl_xor(v, 8));
            float m_new = fmaxf(m_run[r], v);
            scale[r] = __expf(m_run[r] - m_new);
            m_run[r] = m_new;
            p[0][r] = __expf(sc[0][r] - m_new);
            p[1][r] = __expf(sc[1][r] - m_new);
            float s = p[0][r] + p[1][r];
            s += __shfl_xor(s, 1);
            s += __shfl_xor(s, 2);
            s += __shfl_xor(s, 4);
            s += __shfl_xor(s, 8);
            l_run[r] = l_run[r] * scale[r] + s;
        }

        float* pw = Pbuf[wid];
#pragma unroll
        for (int r = 0; r < 4; ++r) {
            pw[(fg * 4 + r) * 36 + fr]      = p[0][r];
            pw[(fg * 4 + r) * 36 + 16 + fr] = p[1][r];
        }
#pragma unroll
        for (int db = 0; db < 4; ++db)
#pragma unroll
            for (int r = 0; r < 4; ++r)
                O[db][r] *= scale[r];

        __syncthreads();

        float pr[8];
        {
            const float* prd = &pw[fr * 36 + fg * 8];
            *(float4*)&pr[0] = *(const float4*)&prd[0];
            *(float4*)&pr[4] = *(const float4*)&prd[4];
        }
        bf16x8 ph8, pl8;
#pragma unroll
        for (int i = 0; i < 8; ++i) {
            unsigned short hi = f2bf(pr[i]);
            ph8[i] = (short)hi;
            pl8[i] = (short)f2bf(pr[i] - bf2f(hi));
        }

#pragma unroll
        for (int db = 0; db < 4; ++db) {
            int idx = (db * 16 + fr) * 40 + fg * 8;
            bf16x8 vh8 = *(const bf16x8*)&Vhi[idx];
            bf16x8 vl8 = *(const bf16x8*)&Vlo[idx];
            O[db] = __builtin_amdgcn_mfma_f32_16x16x32_bf16(ph8, vh8, O[db], 0, 0, 0);
            O[db] = __builtin_amdgcn_mfma_f32_16x16x32_bf16(ph8, vl8, O[db], 0, 0, 0);
            O[db] = __builtin_amdgcn_mfma_f32_16x16x32_bf16(pl8, vh8, O[db], 0, 0, 0);
        }
    }

    float* cbase = ctx + ((size_t)b * SS + q0 + wq0) * D_MODEL + h * DK;
#pragma unroll
    for (int r = 0; r < 4; ++r) {
        float inv = 1.0f / l_run[r];
        int q = fg * 4 + r;
#pragma unroll
        for (int db = 0; db < 4; ++db)
            cbase[(size_t)q * D_MODEL + db * 16 + fr] = O[db][r] * inv;
    }
}

// ---------------------------------------------------------------------------
extern "C" void kernel_launch(void* const* d_in, const int* in_sizes, int n_in,
                              void* d_out, int out_size, void* d_ws, size_t ws_size,
                              hipStream_t stream) {
    const float* q    = (const float*)d_in[0];
    const float* k    = (const float*)d_in[1];
    const float* v    = (const float*)d_in[2];
    const int*   mask = (const int*)d_in[3];
    const float* w_q  = (const float*)d_in[4];
    const float* b_q  = (const float*)d_in[5];
    const float* w_k  = (const float*)d_in[6];
    const float* b_k  = (const float*)d_in[7];
    const float* w_v  = (const float*)d_in[8];
    const float* b_v  = (const float*)d_in[9];
    const float* w_o  = (const float*)d_in[10];
    const float* b_o  = (const float*)d_in[11];
    float* out = (float*)d_out;

    const int M = BB * SS;
    const size_t PSZ = (size_t)M * D_MODEL;
    const size_t NEED = (size_t)208 << 20;
    char* w = (char*)d_ws;
    dim3 block(256);

    if (ws_size >= NEED) {
        unsigned short* qp16 = (unsigned short*)(w);                       // fp16 Q, scaled
        unsigned short* k16  = (unsigned short*)(w + ((size_t)16 << 20));  // fp16 K
        unsigned short* vt16 = (unsigned short*)(w + ((size_t)32 << 20));  // fp16 V^T
        unsigned short* Aq   = (unsigned short*)(w + ((size_t)48 << 20));  // fp16 inputs
        unsigned short* Ak   = (unsigned short*)(w + ((size_t)64 << 20));
        unsigned short* Av   = (unsigned short*)(w + ((size_t)80 << 20));
        unsigned short* Wq   = (unsigned short*)(w + ((size_t)96 << 20));  // fp16 weights
        unsigned short* Wk   = (unsigned short*)(w + ((size_t)98 << 20));
        unsigned short* Wv   = (unsigned short*)(w + ((size_t)100 << 20));
        unsigned short* Wo   = (unsigned short*)(w + ((size_t)102 << 20));
        unsigned short* Ac   = Ak;   // fp16 ctx (Ak dead after K-GEMM)

        const int ACT_CHUNKS = M * 128;
        const int W_CHUNKS   = 1024 * 128;

        SplitJobs8 J{};
        J.j[0] = {q,   Aq, ACT_CHUNKS};
        J.j[1] = {k,   Ak, ACT_CHUNKS};
        J.j[2] = {v,   Av, ACT_CHUNKS};
        J.j[3] = {w_q, Wq, W_CHUNKS};
        J.j[4] = {w_k, Wk, W_CHUNKS};
        J.j[5] = {w_v, Wv, W_CHUNKS};
        J.j[6] = {w_o, Wo, W_CHUNKS};
        presplit<<<dim3(4096, 7), block, 0, stream>>>(J);

        dim3 ggrid(D_MODEL / 128, M / 128);
        gemm_f16<4><<<ggrid, block, 0, stream>>>(Aq, Wq, b_q, nullptr, qp16);
        gemm_f16<2><<<ggrid, block, 0, stream>>>(Ak, Wk, b_k, nullptr, k16);
        gemm_f16<3><<<ggrid, block, 0, stream>>>(Av, Wv, b_v, nullptr, vt16);

        attn_f16<<<dim3(BB * NHEAD * (SS / 128)), dim3(512), 0, stream>>>(
            qp16, k16, vt16, mask, Ac);

        gemm_f16<0><<<ggrid, block, 0, stream>>>(Ac, Wo, b_o, out, nullptr);
    } else {
        float* qp           = (float*)d_ws;
        unsigned short* khi = (unsigned short*)(qp + PSZ);
        unsigned short* klo = khi + PSZ;
        unsigned short* vhi = klo + PSZ;
        unsigned short* vlo = vhi + PSZ;
        float* ctx          = (float*)(vlo + PSZ);

        dim3 grid(D_MODEL / 128, M / 128);
        gemm_xwT<1><<<grid, block, 0, stream>>>(q, w_q, b_q, qp, nullptr, nullptr, M, D_MODEL, D_MODEL);
        gemm_xwT<2><<<grid, block, 0, stream>>>(k, w_k, b_k, nullptr, khi, klo, M, D_MODEL, D_MODEL);
        gemm_xwT<2><<<grid, block, 0, stream>>>(v, w_v, b_v, nullptr, vhi, vlo, M, D_MODEL, D_MODEL);
        attn_mfma<<<dim3(BB * NHEAD * (SS / 64)), block, 0, stream>>>(qp, khi, klo, vhi, vlo, mask, ctx);
        gemm_xwT<0><<<grid, block, 0, stream>>>(ctx, w_o, b_o, out, nullptr, nullptr, M, D_MODEL, D_MODEL);
    }
}

// Round 22
// 238.499 us; speedup vs baseline: 3.3258x; 3.3258x over previous
//
#include <hip/hip_runtime.h>
#include <stdint.h>

#define D_MODEL 1024
#define NHEAD   16
#define DK      64
#define SS      2048
#define BB      4

typedef short bf16x8 __attribute__((ext_vector_type(8)));
typedef _Float16 f16x8 __attribute__((ext_vector_type(8)));
typedef unsigned short u16x8 __attribute__((ext_vector_type(8)));
typedef unsigned short u16x4 __attribute__((ext_vector_type(4)));
typedef float f32x4  __attribute__((ext_vector_type(4)));

#if __has_builtin(__builtin_amdgcn_exp2f)
#define EXP2(x) __builtin_amdgcn_exp2f(x)
#else
#define EXP2(x) __expf((x) * 0.6931471805599453f)
#endif

#define QSCALE_F 0.1803368801111204f   // 0.125 * log2(e)

__device__ inline unsigned short f2bf(float x) {
    unsigned u = __float_as_uint(x);
    return (unsigned short)((u + 0x7fff + ((u >> 16) & 1)) >> 16);
}
__device__ inline float bf2f(unsigned short h) {
    return __uint_as_float(((unsigned)h) << 16);
}
__device__ inline unsigned short f2h(float x) {
    _Float16 h = (_Float16)x;           // v_cvt_f16_f32 (RNE)
    return __builtin_bit_cast(unsigned short, h);
}

__device__ inline void gll16(const void* g, void* l) {
    __builtin_amdgcn_global_load_lds(
        (const __attribute__((address_space(1))) unsigned int*)(g),
        (__attribute__((address_space(3))) unsigned int*)(l),
        16, 0, 0);
}

// ---------------------------------------------------------------------------
// Pre-split: fp32 row-major [R][1024] -> single fp16, tiled-swizzled.
// ---------------------------------------------------------------------------
struct SplitJob { const float* src; unsigned short* dst; int nchunks; };
struct SplitJobs8 { SplitJob j[8]; };

__global__ __launch_bounds__(256) void presplit(SplitJobs8 jobs) {
    const SplitJob J = jobs.j[blockIdx.y];
    int g = blockIdx.x * 256 + threadIdx.x;
    if (g >= J.nchunks) return;
    int tile = g >> 9;
    int w    = g & 511;
    int r    = w >> 2;
    int cc   = w & 3;
    int mt   = tile >> 5;
    int kt   = tile & 31;
    int m    = mt * 128 + r;
    int k0   = kt * 32 + cc * 8;

    const float* s = J.src + (size_t)m * 1024 + k0;
    float4 f0 = *(const float4*)s;
    float4 f1 = *(const float4*)(s + 4);
    float vals[8] = {f0.x, f0.y, f0.z, f0.w, f1.x, f1.y, f1.z, f1.w};
    u16x8 h8;
#pragma unroll
    for (int i = 0; i < 8; ++i) h8[i] = f2h(vals[i]);
    int slot = cc ^ (r & 3) ^ ((r >> 2) & 3);
    size_t doff = (size_t)tile * 4096 + r * 32 + slot * 8;
    *(u16x8*)(J.dst + doff) = h8;
}

// ---------------------------------------------------------------------------
// Single-pass fp16 MFMA GEMM: C = A * W^T + bias.  (validated R17-R20)
// MODE 0: fp32 [M,N]
// MODE 2: fp16 [B,H,S,DK]                      (K for attention)
// MODE 3: fp16 TRANSPOSED [(b*H+h)][d][S]      (V, fused transpose)
// MODE 4: fp16 [B,H,S,DK], scaled by QSCALE    (Q, pre-scaled for softmax)
// ---------------------------------------------------------------------------
template <int MODE>
__global__ __launch_bounds__(256) void gemm_f16(const unsigned short* __restrict__ A,
                                                const unsigned short* __restrict__ B,
                                                const float* __restrict__ bias,
                                                float* __restrict__ C,
                                                unsigned short* __restrict__ C16) {
    __shared__ unsigned short As[4096], Bs[4096];

    const int tid  = threadIdx.x;
    const int lane = tid & 63;
    const int wid  = tid >> 6;
    const int bx   = blockIdx.x;
    const int by   = blockIdx.y;
    const int wr   = wid >> 1;
    const int wc   = wid & 1;
    const int fr   = lane & 15;
    const int fg   = lane >> 4;
    const int chunk = fg ^ (fr & 3) ^ ((fr >> 2) & 3);

    f32x4 acc[4][4] = {};

    const size_t aT = (size_t)by * 32;
    const size_t bT = (size_t)bx * 32;
    const int soff  = wid * 2048 + lane * 16;

    for (int kt = 0; kt < 32; ++kt) {
        const char* at = (const char*)A + ((aT + kt) << 13);
        const char* bt = (const char*)B + ((bT + kt) << 13);
        gll16(at + soff,        (char*)As + soff);
        gll16(at + soff + 1024, (char*)As + soff + 1024);
        gll16(bt + soff,        (char*)Bs + soff);
        gll16(bt + soff + 1024, (char*)Bs + soff + 1024);
        __syncthreads();

        f16x8 ah[4], bh[4];
#pragma unroll
        for (int mi = 0; mi < 4; ++mi) {
            int ro = (wr * 64 + mi * 16 + fr) * 64 + chunk * 16;
            ah[mi] = *(const f16x8*)((const char*)As + ro);
        }
#pragma unroll
        for (int ni = 0; ni < 4; ++ni) {
            int ro = (wc * 64 + ni * 16 + fr) * 64 + chunk * 16;
            bh[ni] = *(const f16x8*)((const char*)Bs + ro);
        }
#pragma unroll
        for (int mi = 0; mi < 4; ++mi)
#pragma unroll
            for (int ni = 0; ni < 4; ++ni)
                acc[mi][ni] = __builtin_amdgcn_mfma_f32_16x16x32_f16(ah[mi], bh[ni], acc[mi][ni], 0, 0, 0);
        __syncthreads();
    }

#pragma unroll
    for (int ni = 0; ni < 4; ++ni) {
        int col = bx * 128 + wc * 64 + ni * 16 + fr;
        float bb = bias[col];
#pragma unroll
        for (int mi = 0; mi < 4; ++mi) {
            if (MODE == 3) {
                int row0 = by * 128 + wr * 64 + mi * 16 + fg * 4;
                int bq = row0 >> 11, s0 = row0 & (SS - 1);
                int h = col >> 6, d = col & 63;
                u16x4 h4;
#pragma unroll
                for (int r2 = 0; r2 < 4; ++r2)
                    h4[r2] = f2h(acc[mi][ni][r2] + bb);
                size_t obase = (((size_t)(bq * NHEAD + h) * 64 + d) * SS + s0);
                *(u16x4*)&C16[obase] = h4;
            } else {
#pragma unroll
                for (int r2 = 0; r2 < 4; ++r2) {
                    int row = by * 128 + wr * 64 + mi * 16 + fg * 4 + r2;
                    float cv = acc[mi][ni][r2] + bb;
                    if (MODE == 0) {
                        C[(size_t)row * D_MODEL + col] = cv;
                    } else {
                        int bq = row >> 11, s = row & (SS - 1), h = col >> 6, d = col & 63;
                        size_t base = (((size_t)(bq * NHEAD + h) * SS + s) << 6) + d;
                        if (MODE == 2) C16[base] = f2h(cv);
                        else           C16[base] = f2h(cv * QSCALE_F);   // MODE 4
                    }
                }
            }
        }
    }
}

// ---------------------------------------------------------------------------
// fp16 flash attention v6: exact R20 structure (KVBLK=128, fp16 Pbuf,
// fixed-max softmax, NO forced launch-bounds min — R21's (512,8) forced a
// 32-VGPR allocation with 1.8GB of scratch spill). VGPR squeezed at SOURCE:
// p[4][4] staging array deleted (EXP2 fused into the Pbuf write loop) and
// the nomask branch duplication removed -> target <=64 VGPR -> 8 waves/SIMD
// -> 4 blocks/CU -> capacity 1024 = grid -> one residency round.
// ---------------------------------------------------------------------------
__global__ __launch_bounds__(512) void attn_f16(const unsigned short* __restrict__ Q16,
                                                const unsigned short* __restrict__ K16,
                                                const unsigned short* __restrict__ VT16,
                                                const int* __restrict__ mask,
                                                unsigned short* __restrict__ Ac) {
    __shared__ unsigned short Ks[8192];   // [128 key][64 d], 8-slot swz per row
    __shared__ unsigned short Vs[8192];   // [64 d][128 key], 16-slot swz per row
    __shared__ unsigned short Pb[8][16 * 32];   // fp16 P, chunk-XOR swizzled

    const int tid  = threadIdx.x;
    const int lane = tid & 63;
    const int wid  = tid >> 6;

    const int bid = blockIdx.x;
    const int swz = (bid & 7) * 128 + (bid >> 3);
    const int qt  = swz & 15;
    const int bh  = swz >> 4;
    const int b   = bh >> 4;
    const int h   = bh & 15;

    const int q0  = qt * 128;
    const int wq0 = wid * 16;

    const int fr = lane & 15;
    const int fg = lane >> 4;

    const unsigned short* qb   = Q16 + ((size_t)bh * SS + q0 + wq0) * DK;
    const unsigned short* kb16 = K16 + (size_t)bh * SS * DK;
    const unsigned short* vb16 = VT16 + (size_t)bh * DK * SS;
    const int* mrow = mask + b * SS;

    // Q fragments: direct fp16 loads (already scaled)
    f16x8 qf[2];
#pragma unroll
    for (int kb = 0; kb < 2; ++kb)
        qf[kb] = *(const f16x8*)&qb[(size_t)fr * DK + kb * 32 + fg * 8];

    f16x8 ONES16;
#pragma unroll
    for (int i = 0; i < 8; ++i) ONES16[i] = (_Float16)1.0f;

    f32x4 O[4] = {};
    f32x4 Lacc = {};

    // staging: 1024 chunks per array, 2 per thread per array
    const int c0 = tid, c1 = tid + 512;
    const int k0r = c0 >> 3, k0s = c0 & 7;
    const int k1r = c1 >> 3, k1s = c1 & 7;
    const int k0d = k0r * 64 + ((k0s ^ (k0r & 7)) << 3);
    const int k1d = k1r * 64 + ((k1s ^ (k1r & 7)) << 3);
    const int k0g = k0r * 64 + k0s * 8;      // + kv0*64
    const int k1g = k1r * 64 + k1s * 8;
    const int v0r = c0 >> 4, v0s = c0 & 15;
    const int v1r = c1 >> 4, v1s = c1 & 15;
    const int v0d = v0r * 128 + ((v0s ^ (v0r & 15)) << 3);
    const int v1d = v1r * 128 + ((v1s ^ (v1r & 15)) << 3);
    const int v0g = v0r * SS + v0s * 8;      // + kv0
    const int v1g = v1r * SS + v1s * 8;

    const int sl0 = ((0 + fg) ^ (fr & 7)) * 8;
    const int sl1 = ((4 + fg) ^ (fr & 7)) * 8;

    unsigned short* pw16 = Pb[wid];
    // P read: single 16B chunk, logical chunk fg, swizzled by row(fr)&3
    const int prd_off = fr * 32 + ((fg ^ (fr & 3)) << 3);

    // prologue: stage tile 0 into regs
    u16x8 rK0 = *(const u16x8*)&kb16[k0g];
    u16x8 rK1 = *(const u16x8*)&kb16[k1g];
    u16x8 rV0 = *(const u16x8*)&vb16[v0g];
    u16x8 rV1 = *(const u16x8*)&vb16[v1g];

    for (int t = 0; t < SS / 128; ++t) {
        const int kv0 = t * 128;

        __syncthreads();   // previous tile's LDS reads complete
        *(u16x8*)&Ks[k0d] = rK0;
        *(u16x8*)&Ks[k1d] = rK1;
        *(u16x8*)&Vs[v0d] = rV0;
        *(u16x8*)&Vs[v1d] = rV1;
        __syncthreads();   // tile t visible

        if (t + 1 < SS / 128) {
            const int kn = kv0 + 128;
            rK0 = *(const u16x8*)&kb16[(size_t)kn * 64 + k0g];
            rK1 = *(const u16x8*)&kb16[(size_t)kn * 64 + k1g];
            rV0 = *(const u16x8*)&vb16[v0g + kn];
            rV1 = *(const u16x8*)&vb16[v1g + kn];
        }

        // two 64-key sub-tiles
#pragma unroll
        for (int sub = 0; sub < 2; ++sub) {
            const int kvs = kv0 + sub * 64;

            int mv[4];
#pragma unroll
            for (int kyb = 0; kyb < 4; ++kyb) mv[kyb] = mrow[kvs + kyb * 16 + fr];

            // --- QK^T: 8 MFMA
            f32x4 acc[4] = {};
            __builtin_amdgcn_s_setprio(1);
#pragma unroll
            for (int kyb = 0; kyb < 4; ++kyb) {
                const int rb = (sub * 64 + kyb * 16 + fr) * 64;
                f16x8 k0 = *(const f16x8*)&Ks[rb + sl0];
                f16x8 k1 = *(const f16x8*)&Ks[rb + sl1];
                acc[kyb] = __builtin_amdgcn_mfma_f32_16x16x32_f16(qf[0], k0, acc[kyb], 0, 0, 0);
                acc[kyb] = __builtin_amdgcn_mfma_f32_16x16x32_f16(qf[1], k1, acc[kyb], 0, 0, 0);
            }
            __builtin_amdgcn_s_setprio(0);

            // --- two PV half-phases; fixed-max softmax (p = exp2(score),
            //     mask -> 0) fused directly into the Pbuf write (no p[][]).
#pragma unroll
            for (int ph2 = 0; ph2 < 2; ++ph2) {
#pragma unroll
                for (int kyb2 = 0; kyb2 < 2; ++kyb2) {
                    const int kyb = ph2 * 2 + kyb2;
#pragma unroll
                    for (int r = 0; r < 4; ++r) {
                        int row = fg * 4 + r;
                        int co  = kyb2 * 16 + fr;
                        int ch  = (co >> 3) ^ (row & 3);
                        float pv = mv[kyb] ? EXP2(acc[kyb][r]) : 0.f;
                        pw16[row * 32 + ch * 8 + (co & 7)] = f2h(pv);
                    }
                }

                asm volatile("s_waitcnt lgkmcnt(0)" ::: "memory");
                __builtin_amdgcn_sched_barrier(0);

                f16x8 pf = *(const f16x8*)&pw16[prd_off];

                // V logical key-chunk: sub*8 + ph2*4 + fg, swizzled by row&15=fr
                const int vsl = (((sub * 8 + ph2 * 4 + fg) ^ (fr & 15)) << 3);
                __builtin_amdgcn_s_setprio(1);
                Lacc = __builtin_amdgcn_mfma_f32_16x16x32_f16(pf, ONES16, Lacc, 0, 0, 0);
#pragma unroll
                for (int db = 0; db < 4; ++db) {
                    const int rb = (db * 16 + fr) * 128 + vsl;
                    f16x8 vf = *(const f16x8*)&Vs[rb];
                    O[db] = __builtin_amdgcn_mfma_f32_16x16x32_f16(pf, vf, O[db], 0, 0, 0);
                }
                __builtin_amdgcn_s_setprio(0);

                // WAR fence: Pbuf reads retired before next writes
                asm volatile("s_waitcnt lgkmcnt(0)" ::: "memory");
                __builtin_amdgcn_sched_barrier(0);
            }
        }
    }

    // --- epilogue: fp16 tiled-swizzled ctx store
#pragma unroll
    for (int r = 0; r < 4; ++r) {
        float inv = 1.0f / Lacc[r];
        int m  = b * SS + q0 + wq0 + fg * 4 + r;
        int rt = m & 127;
        int mt = m >> 7;
        int rx = (rt & 3) ^ ((rt >> 2) & 3);
#pragma unroll
        for (int db = 0; db < 4; ++db) {
            float val = O[db][r] * inv;
            int kcol = h * 64 + db * 16 + fr;
            int tile = mt * 32 + (kcol >> 5);
            int slot = (((kcol >> 3) & 3)) ^ rx;
            size_t doff = (size_t)tile * 4096 + rt * 32 + slot * 8 + (kcol & 7);
            Ac[doff] = f2h(val);
        }
    }
}

// ---------------------------------------------------------------------------
// fp32 GEMM + old attention (fallback path, unchanged/validated)
// ---------------------------------------------------------------------------
template <int MODE>
__global__ __launch_bounds__(256) void gemm_xwT(const float* __restrict__ A,
                                                const float* __restrict__ W,
                                                const float* __restrict__ bias,
                                                float* __restrict__ C,
                                                unsigned short* __restrict__ Chi,
                                                unsigned short* __restrict__ Clo,
                                                int M, int N, int K) {
    __shared__ float As[8][132];
    __shared__ float Bs[8][132];

    const int tid = threadIdx.x;
    const int tx  = tid & 15;
    const int ty  = tid >> 4;
    const int m0  = blockIdx.y * 128;
    const int n0  = blockIdx.x * 128;

    const int lr = tid >> 1;
    const int lk = (tid & 1) * 4;

    float acc[8][8];
#pragma unroll
    for (int i = 0; i < 8; ++i)
#pragma unroll
        for (int j = 0; j < 8; ++j) acc[i][j] = 0.f;

    for (int kt = 0; kt < K; kt += 8) {
        float4 av = *(const float4*)&A[(size_t)(m0 + lr) * K + kt + lk];
        float4 wv = *(const float4*)&W[(size_t)(n0 + lr) * K + kt + lk];
        __syncthreads();
        As[lk + 0][lr] = av.x; As[lk + 1][lr] = av.y;
        As[lk + 2][lr] = av.z; As[lk + 3][lr] = av.w;
        Bs[lk + 0][lr] = wv.x; Bs[lk + 1][lr] = wv.y;
        Bs[lk + 2][lr] = wv.z; Bs[lk + 3][lr] = wv.w;
        __syncthreads();
#pragma unroll
        for (int k = 0; k < 8; ++k) {
            float4 a0 = *(const float4*)&As[k][ty * 8];
            float4 a1 = *(const float4*)&As[k][ty * 8 + 4];
            float4 b0 = *(const float4*)&Bs[k][tx * 8];
            float4 b1 = *(const float4*)&Bs[k][tx * 8 + 4];
            float a[8] = {a0.x, a0.y, a0.z, a0.w, a1.x, a1.y, a1.z, a1.w};
            float b[8] = {b0.x, b0.y, b0.z, b0.w, b1.x, b1.y, b1.z, b1.w};
#pragma unroll
            for (int i = 0; i < 8; ++i)
#pragma unroll
                for (int j = 0; j < 8; ++j) acc[i][j] += a[i] * b[j];
        }
    }

    float bb[8];
#pragma unroll
    for (int j = 0; j < 8; ++j) bb[j] = bias[n0 + tx * 8 + j];

#pragma unroll
    for (int i = 0; i < 8; ++i) {
        int m = m0 + ty * 8 + i;
        int n = n0 + tx * 8;
        float cv[8];
#pragma unroll
        for (int j = 0; j < 8; ++j) cv[j] = acc[i][j] + bb[j];

        if (MODE == 0) {
            float* dst = &C[(size_t)m * N + n];
            *(float4*)&dst[0] = {cv[0], cv[1], cv[2], cv[3]};
            *(float4*)&dst[4] = {cv[4], cv[5], cv[6], cv[7]};
        } else {
            int bq = m >> 11;
            int s  = m & (SS - 1);
            int h  = n >> 6;
            int d  = n & 63;
            size_t base = (((size_t)(bq * NHEAD + h) * SS + s) << 6) + d;
            if (MODE == 1) {
                float* dst = &C[base];
                *(float4*)&dst[0] = {cv[0], cv[1], cv[2], cv[3]};
                *(float4*)&dst[4] = {cv[4], cv[5], cv[6], cv[7]};
            } else {
                u16x8 h8, l8;
#pragma unroll
                for (int j = 0; j < 8; ++j) {
                    unsigned short hv = f2bf(cv[j]);
                    h8[j] = hv;
                    l8[j] = f2bf(cv[j] - bf2f(hv));
                }
                *(u16x8*)&Chi[base] = h8;
                *(u16x8*)&Clo[base] = l8;
            }
        }
    }
}

__global__ __launch_bounds__(256) void attn_mfma(const float* __restrict__ Qp,
                                                 const unsigned short* __restrict__ Khig,
                                                 const unsigned short* __restrict__ Klog,
                                                 const unsigned short* __restrict__ Vhig,
                                                 const unsigned short* __restrict__ Vlog,
                                                 const int* __restrict__ mask,
                                                 float* __restrict__ ctx) {
    __shared__ short Khi[32 * 72], Klo[32 * 72];
    __shared__ short Vhi[64 * 40], Vlo[64 * 40];
    __shared__ float Pbuf[4][16 * 36];
    __shared__ int   msk[32];

    const int tid  = threadIdx.x;
    const int lane = tid & 63;
    const int wid  = tid >> 6;

    const int bid = blockIdx.x;
    const int swz = (bid & 7) * 256 + (bid >> 3);
    const int qt  = swz & 31;
    const int bh  = swz >> 5;
    const int b   = bh >> 4;
    const int h   = bh & 15;

    const int q0  = qt * 64;
    const int wq0 = wid * 16;

    const int fr = lane & 15;
    const int fg = lane >> 4;

    const float* qbase = Qp + ((size_t)bh * SS + q0 + wq0) * DK;
    const unsigned short* khbase = Khig + (size_t)bh * SS * DK;
    const unsigned short* klbase = Klog + (size_t)bh * SS * DK;
    const unsigned short* vhbase = Vhig + (size_t)bh * SS * DK;
    const unsigned short* vlbase = Vlog + (size_t)bh * SS * DK;
    const int* mrow = mask + b * SS;

    bf16x8 qh[2], ql[2];
#pragma unroll
    for (int kb = 0; kb < 2; ++kb) {
        const float* p = qbase + (size_t)fr * DK + kb * 32 + fg * 8;
        float4 a  = *(const float4*)p;
        float4 b4 = *(const float4*)(p + 4);
        float vals[8] = {a.x, a.y, a.z, a.w, b4.x, b4.y, b4.z, b4.w};
#pragma unroll
        for (int i = 0; i < 8; ++i) {
            float s = vals[i] * 0.125f;
            unsigned short hi = f2bf(s);
            qh[kb][i] = (short)hi;
            ql[kb][i] = (short)f2bf(s - bf2f(hi));
        }
    }

    f32x4 O[4] = {};
    float m_run[4], l_run[4];
#pragma unroll
    for (int r = 0; r < 4; ++r) { m_run[r] = -3.0e38f; l_run[r] = 0.f; }

    const int sk_k = tid >> 3;
    const int sk_d = (tid & 7) * 8;
    const int sv_d = tid & 63;
    const int sv_k = (tid >> 6) * 8;

    for (int t = 0; t < SS / 32; ++t) {
        const int kv0 = t * 32;

        size_t koff = (size_t)(kv0 + sk_k) * DK + sk_d;
        u16x8 kh8 = *(const u16x8*)&khbase[koff];
        u16x8 kl8 = *(const u16x8*)&klbase[koff];
        unsigned short vh[8], vl[8];
#pragma unroll
        for (int j = 0; j < 8; ++j) {
            size_t voff = (size_t)(kv0 + sv_k + j) * DK + sv_d;
            vh[j] = vhbase[voff];
            vl[j] = vlbase[voff];
        }
        int mval = (tid < 32) ? mrow[kv0 + tid] : 0;

        __syncthreads();
        *(u16x8*)&Khi[sk_k * 72 + sk_d] = kh8;
        *(u16x8*)&Klo[sk_k * 72 + sk_d] = kl8;
        {
            u16x8 h8, l8;
#pragma unroll
            for (int j = 0; j < 8; ++j) { h8[j] = vh[j]; l8[j] = vl[j]; }
            *(u16x8*)&Vhi[sv_d * 40 + sv_k] = h8;
            *(u16x8*)&Vlo[sv_d * 40 + sv_k] = l8;
        }
        if (tid < 32) msk[tid] = mval;
        __syncthreads();

        f32x4 acc[2] = {};
#pragma unroll
        for (int kyb = 0; kyb < 2; ++kyb) {
#pragma unroll
            for (int kb = 0; kb < 2; ++kb) {
                int idx = (kyb * 16 + fr) * 72 + kb * 32 + fg * 8;
                bf16x8 kh = *(const bf16x8*)&Khi[idx];
                bf16x8 kl = *(const bf16x8*)&Klo[idx];
                acc[kyb] = __builtin_amdgcn_mfma_f32_16x16x32_bf16(qh[kb], kh, acc[kyb], 0, 0, 0);
                acc[kyb] = __builtin_amdgcn_mfma_f32_16x16x32_bf16(qh[kb], kl, acc[kyb], 0, 0, 0);
                acc[kyb] = __builtin_amdgcn_mfma_f32_16x16x32_bf16(ql[kb], kh, acc[kyb], 0, 0, 0);
            }
        }

        float sc[2][4];
#pragma unroll
        for (int kyb = 0; kyb < 2; ++kyb) {
            int mv = msk[kyb * 16 + fr];
#pragma unroll
            for (int r = 0; r < 4; ++r)
                sc[kyb][r] = mv ? acc[kyb][r] : -1.0e9f;
        }
        float scale[4], p[2][4];
#pragma unroll
        for (int r = 0; r < 4; ++r) {
            float v = fmaxf(sc[0][r], sc[1][r]);
            v = fmaxf(v, __shfl_xor(v, 1));
            v = fmaxf(v, __shfl_xor(v, 2));
            v = fmaxf(v, __shfl_xor(v, 4));
            v = fmaxf(v, __shfl_xor(v, 8));
            float m_new = fmaxf(m_run[r], v);
            scale[r] = __expf(m_run[r] - m_new);
            m_run[r] = m_new;
            p[0][r] = __expf(sc[0][r] - m_new);
            p[1][r] = __expf(sc[1][r] - m_new);
            float s = p[0][r] + p[1][r];
            s += __shfl_xor(s, 1);
            s += __shfl_xor(s, 2);
            s += __shfl_xor(s, 4);
            s += __shfl_xor(s, 8);
            l_run[r] = l_run[r] * scale[r] + s;
        }

        float* pw = Pbuf[wid];
#pragma unroll
        for (int r = 0; r < 4; ++r) {
            pw[(fg * 4 + r) * 36 + fr]      = p[0][r];
            pw[(fg * 4 + r) * 36 + 16 + fr] = p[1][r];
        }
#pragma unroll
        for (int db = 0; db < 4; ++db)
#pragma unroll
            for (int r = 0; r < 4; ++r)
                O[db][r] *= scale[r];

        __syncthreads();

        float pr[8];
        {
            const float* prd = &pw[fr * 36 + fg * 8];
            *(float4*)&pr[0] = *(const float4*)&prd[0];
            *(float4*)&pr[4] = *(const float4*)&prd[4];
        }
        bf16x8 ph8, pl8;
#pragma unroll
        for (int i = 0; i < 8; ++i) {
            unsigned short hi = f2bf(pr[i]);
            ph8[i] = (short)hi;
            pl8[i] = (short)f2bf(pr[i] - bf2f(hi));
        }

#pragma unroll
        for (int db = 0; db < 4; ++db) {
            int idx = (db * 16 + fr) * 40 + fg * 8;
            bf16x8 vh8 = *(const bf16x8*)&Vhi[idx];
            bf16x8 vl8 = *(const bf16x8*)&Vlo[idx];
            O[db] = __builtin_amdgcn_mfma_f32_16x16x32_bf16(ph8, vh8, O[db], 0, 0, 0);
            O[db] = __builtin_amdgcn_mfma_f32_16x16x32_bf16(ph8, vl8, O[db], 0, 0, 0);
            O[db] = __builtin_amdgcn_mfma_f32_16x16x32_bf16(pl8, vh8, O[db], 0, 0, 0);
        }
    }

    float* cbase = ctx + ((size_t)b * SS + q0 + wq0) * D_MODEL + h * DK;
#pragma unroll
    for (int r = 0; r < 4; ++r) {
        float inv = 1.0f / l_run[r];
        int q = fg * 4 + r;
#pragma unroll
        for (int db = 0; db < 4; ++db)
            cbase[(size_t)q * D_MODEL + db * 16 + fr] = O[db][r] * inv;
    }
}

// ---------------------------------------------------------------------------
extern "C" void kernel_launch(void* const* d_in, const int* in_sizes, int n_in,
                              void* d_out, int out_size, void* d_ws, size_t ws_size,
                              hipStream_t stream) {
    const float* q    = (const float*)d_in[0];
    const float* k    = (const float*)d_in[1];
    const float* v    = (const float*)d_in[2];
    const int*   mask = (const int*)d_in[3];
    const float* w_q  = (const float*)d_in[4];
    const float* b_q  = (const float*)d_in[5];
    const float* w_k  = (const float*)d_in[6];
    const float* b_k  = (const float*)d_in[7];
    const float* w_v  = (const float*)d_in[8];
    const float* b_v  = (const float*)d_in[9];
    const float* w_o  = (const float*)d_in[10];
    const float* b_o  = (const float*)d_in[11];
    float* out = (float*)d_out;

    const int M = BB * SS;
    const size_t PSZ = (size_t)M * D_MODEL;
    const size_t NEED = (size_t)208 << 20;
    char* w = (char*)d_ws;
    dim3 block(256);

    if (ws_size >= NEED) {
        unsigned short* qp16 = (unsigned short*)(w);                       // fp16 Q, scaled
        unsigned short* k16  = (unsigned short*)(w + ((size_t)16 << 20));  // fp16 K
        unsigned short* vt16 = (unsigned short*)(w + ((size_t)32 << 20));  // fp16 V^T
        unsigned short* Aq   = (unsigned short*)(w + ((size_t)48 << 20));  // fp16 inputs
        unsigned short* Ak   = (unsigned short*)(w + ((size_t)64 << 20));
        unsigned short* Av   = (unsigned short*)(w + ((size_t)80 << 20));
        unsigned short* Wq   = (unsigned short*)(w + ((size_t)96 << 20));  // fp16 weights
        unsigned short* Wk   = (unsigned short*)(w + ((size_t)98 << 20));
        unsigned short* Wv   = (unsigned short*)(w + ((size_t)100 << 20));
        unsigned short* Wo   = (unsigned short*)(w + ((size_t)102 << 20));
        unsigned short* Ac   = Ak;   // fp16 ctx (Ak dead after K-GEMM)

        const int ACT_CHUNKS = M * 128;
        const int W_CHUNKS   = 1024 * 128;

        SplitJobs8 J{};
        J.j[0] = {q,   Aq, ACT_CHUNKS};
        J.j[1] = {k,   Ak, ACT_CHUNKS};
        J.j[2] = {v,   Av, ACT_CHUNKS};
        J.j[3] = {w_q, Wq, W_CHUNKS};
        J.j[4] = {w_k, Wk, W_CHUNKS};
        J.j[5] = {w_v, Wv, W_CHUNKS};
        J.j[6] = {w_o, Wo, W_CHUNKS};
        presplit<<<dim3(4096, 7), block, 0, stream>>>(J);

        dim3 ggrid(D_MODEL / 128, M / 128);
        gemm_f16<4><<<ggrid, block, 0, stream>>>(Aq, Wq, b_q, nullptr, qp16);
        gemm_f16<2><<<ggrid, block, 0, stream>>>(Ak, Wk, b_k, nullptr, k16);
        gemm_f16<3><<<ggrid, block, 0, stream>>>(Av, Wv, b_v, nullptr, vt16);

        attn_f16<<<dim3(BB * NHEAD * (SS / 128)), dim3(512), 0, stream>>>(
            qp16, k16, vt16, mask, Ac);

        gemm_f16<0><<<ggrid, block, 0, stream>>>(Ac, Wo, b_o, out, nullptr);
    } else {
        float* qp           = (float*)d_ws;
        unsigned short* khi = (unsigned short*)(qp + PSZ);
        unsigned short* klo = khi + PSZ;
        unsigned short* vhi = klo + PSZ;
        unsigned short* vlo = vhi + PSZ;
        float* ctx          = (float*)(vlo + PSZ);

        dim3 grid(D_MODEL / 128, M / 128);
        gemm_xwT<1><<<grid, block, 0, stream>>>(q, w_q, b_q, qp, nullptr, nullptr, M, D_MODEL, D_MODEL);
        gemm_xwT<2><<<grid, block, 0, stream>>>(k, w_k, b_k, nullptr, khi, klo, M, D_MODEL, D_MODEL);
        gemm_xwT<2><<<grid, block, 0, stream>>>(v, w_v, b_v, nullptr, vhi, vlo, M, D_MODEL, D_MODEL);
        attn_mfma<<<dim3(BB * NHEAD * (SS / 64)), block, 0, stream>>>(qp, khi, klo, vhi, vlo, mask, ctx);
        gemm_xwT<0><<<grid, block, 0, stream>>>(ctx, w_o, b_o, out, nullptr, nullptr, M, D_MODEL, D_MODEL);
    }
}

// Round 23
// 229.519 us; speedup vs baseline: 3.4559x; 1.0391x over previous
//
#include <hip/hip_runtime.h>
#include <stdint.h>

#define D_MODEL 1024
#define NHEAD   16
#define DK      64
#define SS      2048
#define BB      4

typedef short bf16x8 __attribute__((ext_vector_type(8)));
typedef _Float16 f16x8 __attribute__((ext_vector_type(8)));
typedef unsigned short u16x8 __attribute__((ext_vector_type(8)));
typedef unsigned short u16x4 __attribute__((ext_vector_type(4)));
typedef float f32x4  __attribute__((ext_vector_type(4)));

#if __has_builtin(__builtin_amdgcn_exp2f)
#define EXP2(x) __builtin_amdgcn_exp2f(x)
#else
#define EXP2(x) __expf((x) * 0.6931471805599453f)
#endif

#define QSCALE_F 0.1803368801111204f   // 0.125 * log2(e)

__device__ inline unsigned short f2bf(float x) {
    unsigned u = __float_as_uint(x);
    return (unsigned short)((u + 0x7fff + ((u >> 16) & 1)) >> 16);
}
__device__ inline float bf2f(unsigned short h) {
    return __uint_as_float(((unsigned)h) << 16);
}
__device__ inline unsigned short f2h(float x) {
    _Float16 h = (_Float16)x;           // v_cvt_f16_f32 (RNE)
    return __builtin_bit_cast(unsigned short, h);
}

__device__ inline void gll16(const void* g, void* l) {
    __builtin_amdgcn_global_load_lds(
        (const __attribute__((address_space(1))) unsigned int*)(g),
        (__attribute__((address_space(3))) unsigned int*)(l),
        16, 0, 0);
}

// ---------------------------------------------------------------------------
// Pre-split: fp32 row-major [R][1024] -> single fp16, tiled-swizzled.
// ---------------------------------------------------------------------------
struct SplitJob { const float* src; unsigned short* dst; int nchunks; };
struct SplitJobs8 { SplitJob j[8]; };

__global__ __launch_bounds__(256) void presplit(SplitJobs8 jobs) {
    const SplitJob J = jobs.j[blockIdx.y];
    int g = blockIdx.x * 256 + threadIdx.x;
    if (g >= J.nchunks) return;
    int tile = g >> 9;
    int w    = g & 511;
    int r    = w >> 2;
    int cc   = w & 3;
    int mt   = tile >> 5;
    int kt   = tile & 31;
    int m    = mt * 128 + r;
    int k0   = kt * 32 + cc * 8;

    const float* s = J.src + (size_t)m * 1024 + k0;
    float4 f0 = *(const float4*)s;
    float4 f1 = *(const float4*)(s + 4);
    float vals[8] = {f0.x, f0.y, f0.z, f0.w, f1.x, f1.y, f1.z, f1.w};
    u16x8 h8;
#pragma unroll
    for (int i = 0; i < 8; ++i) h8[i] = f2h(vals[i]);
    int slot = cc ^ (r & 3) ^ ((r >> 2) & 3);
    size_t doff = (size_t)tile * 4096 + r * 32 + slot * 8;
    *(u16x8*)(J.dst + doff) = h8;
}

// ---------------------------------------------------------------------------
// Fused Q/K/V fp16 GEMM: grid.z in {0,1,2} selects operand set + epilogue:
// z=0: Q -> fp16 [B,H,S,DK] scaled by QSCALE
// z=1: K -> fp16 [B,H,S,DK]
// z=2: V -> fp16 TRANSPOSED [(b*H+h)][d][S]
// 1536 blocks (vs 3x512) -> ~6 blocks/CU: fills the machine, overlaps the
// three projections' staging and compute.
// ---------------------------------------------------------------------------
__global__ __launch_bounds__(256) void gemm_qkv(const unsigned short* __restrict__ Aq,
                                                const unsigned short* __restrict__ Ak,
                                                const unsigned short* __restrict__ Av,
                                                const unsigned short* __restrict__ Wq,
                                                const unsigned short* __restrict__ Wk,
                                                const unsigned short* __restrict__ Wv,
                                                const float* __restrict__ bq,
                                                const float* __restrict__ bk,
                                                const float* __restrict__ bv,
                                                unsigned short* __restrict__ Oq,
                                                unsigned short* __restrict__ Ok,
                                                unsigned short* __restrict__ Ov) {
    __shared__ unsigned short As[4096], Bs[4096];

    const int z = blockIdx.z;
    const unsigned short* A = (z == 0) ? Aq : (z == 1) ? Ak : Av;
    const unsigned short* B = (z == 0) ? Wq : (z == 1) ? Wk : Wv;
    const float* bias       = (z == 0) ? bq : (z == 1) ? bk : bv;
    unsigned short* C16     = (z == 0) ? Oq : (z == 1) ? Ok : Ov;

    const int tid  = threadIdx.x;
    const int lane = tid & 63;
    const int wid  = tid >> 6;
    const int bx   = blockIdx.x;
    const int by   = blockIdx.y;
    const int wr   = wid >> 1;
    const int wc   = wid & 1;
    const int fr   = lane & 15;
    const int fg   = lane >> 4;
    const int chunk = fg ^ (fr & 3) ^ ((fr >> 2) & 3);

    f32x4 acc[4][4] = {};

    const size_t aT = (size_t)by * 32;
    const size_t bT = (size_t)bx * 32;
    const int soff  = wid * 2048 + lane * 16;

    for (int kt = 0; kt < 32; ++kt) {
        const char* at = (const char*)A + ((aT + kt) << 13);
        const char* bt = (const char*)B + ((bT + kt) << 13);
        gll16(at + soff,        (char*)As + soff);
        gll16(at + soff + 1024, (char*)As + soff + 1024);
        gll16(bt + soff,        (char*)Bs + soff);
        gll16(bt + soff + 1024, (char*)Bs + soff + 1024);
        __syncthreads();

        f16x8 ah[4], bh[4];
#pragma unroll
        for (int mi = 0; mi < 4; ++mi) {
            int ro = (wr * 64 + mi * 16 + fr) * 64 + chunk * 16;
            ah[mi] = *(const f16x8*)((const char*)As + ro);
        }
#pragma unroll
        for (int ni = 0; ni < 4; ++ni) {
            int ro = (wc * 64 + ni * 16 + fr) * 64 + chunk * 16;
            bh[ni] = *(const f16x8*)((const char*)Bs + ro);
        }
#pragma unroll
        for (int mi = 0; mi < 4; ++mi)
#pragma unroll
            for (int ni = 0; ni < 4; ++ni)
                acc[mi][ni] = __builtin_amdgcn_mfma_f32_16x16x32_f16(ah[mi], bh[ni], acc[mi][ni], 0, 0, 0);
        __syncthreads();
    }

#pragma unroll
    for (int ni = 0; ni < 4; ++ni) {
        int col = bx * 128 + wc * 64 + ni * 16 + fr;
        float bb = bias[col];
#pragma unroll
        for (int mi = 0; mi < 4; ++mi) {
            if (z == 2) {
                // V: transposed fp16 [(b*H+h)][d][S], packed 8B stores
                int row0 = by * 128 + wr * 64 + mi * 16 + fg * 4;
                int bq2 = row0 >> 11, s0 = row0 & (SS - 1);
                int h = col >> 6, d = col & 63;
                u16x4 h4;
#pragma unroll
                for (int r2 = 0; r2 < 4; ++r2)
                    h4[r2] = f2h(acc[mi][ni][r2] + bb);
                size_t obase = (((size_t)(bq2 * NHEAD + h) * 64 + d) * SS + s0);
                *(u16x4*)&C16[obase] = h4;
            } else {
                const float sc = (z == 0) ? QSCALE_F : 1.0f;
#pragma unroll
                for (int r2 = 0; r2 < 4; ++r2) {
                    int row = by * 128 + wr * 64 + mi * 16 + fg * 4 + r2;
                    float cv = (acc[mi][ni][r2] + bb) * sc;
                    int bq2 = row >> 11, s = row & (SS - 1), h = col >> 6, d = col & 63;
                    size_t base = (((size_t)(bq2 * NHEAD + h) * SS + s) << 6) + d;
                    C16[base] = f2h(cv);
                }
            }
        }
    }
}

// ---------------------------------------------------------------------------
// fp16 GEMM for Wo: C(fp32 [M,N]) = A * W^T + bias   (validated R17-R22)
// ---------------------------------------------------------------------------
__global__ __launch_bounds__(256) void gemm_wo(const unsigned short* __restrict__ A,
                                               const unsigned short* __restrict__ B,
                                               const float* __restrict__ bias,
                                               float* __restrict__ C) {
    __shared__ unsigned short As[4096], Bs[4096];

    const int tid  = threadIdx.x;
    const int lane = tid & 63;
    const int wid  = tid >> 6;
    const int bx   = blockIdx.x;
    const int by   = blockIdx.y;
    const int wr   = wid >> 1;
    const int wc   = wid & 1;
    const int fr   = lane & 15;
    const int fg   = lane >> 4;
    const int chunk = fg ^ (fr & 3) ^ ((fr >> 2) & 3);

    f32x4 acc[4][4] = {};

    const size_t aT = (size_t)by * 32;
    const size_t bT = (size_t)bx * 32;
    const int soff  = wid * 2048 + lane * 16;

    for (int kt = 0; kt < 32; ++kt) {
        const char* at = (const char*)A + ((aT + kt) << 13);
        const char* bt = (const char*)B + ((bT + kt) << 13);
        gll16(at + soff,        (char*)As + soff);
        gll16(at + soff + 1024, (char*)As + soff + 1024);
        gll16(bt + soff,        (char*)Bs + soff);
        gll16(bt + soff + 1024, (char*)Bs + soff + 1024);
        __syncthreads();

        f16x8 ah[4], bh[4];
#pragma unroll
        for (int mi = 0; mi < 4; ++mi) {
            int ro = (wr * 64 + mi * 16 + fr) * 64 + chunk * 16;
            ah[mi] = *(const f16x8*)((const char*)As + ro);
        }
#pragma unroll
        for (int ni = 0; ni < 4; ++ni) {
            int ro = (wc * 64 + ni * 16 + fr) * 64 + chunk * 16;
            bh[ni] = *(const f16x8*)((const char*)Bs + ro);
        }
#pragma unroll
        for (int mi = 0; mi < 4; ++mi)
#pragma unroll
            for (int ni = 0; ni < 4; ++ni)
                acc[mi][ni] = __builtin_amdgcn_mfma_f32_16x16x32_f16(ah[mi], bh[ni], acc[mi][ni], 0, 0, 0);
        __syncthreads();
    }

#pragma unroll
    for (int ni = 0; ni < 4; ++ni) {
        int col = bx * 128 + wc * 64 + ni * 16 + fr;
        float bb = bias[col];
#pragma unroll
        for (int mi = 0; mi < 4; ++mi)
#pragma unroll
            for (int r2 = 0; r2 < 4; ++r2) {
                int row = by * 128 + wr * 64 + mi * 16 + fg * 4 + r2;
                C[(size_t)row * D_MODEL + col] = acc[mi][ni][r2] + bb;
            }
    }
}

// ---------------------------------------------------------------------------
// fp16 flash attention v6 (validated R22: 120us, VGPR 56, 4 blocks/CU).
// KVBLK=128, fp16 Pbuf (40960B LDS), fixed-max softmax fused into P-write.
// ---------------------------------------------------------------------------
__global__ __launch_bounds__(512) void attn_f16(const unsigned short* __restrict__ Q16,
                                                const unsigned short* __restrict__ K16,
                                                const unsigned short* __restrict__ VT16,
                                                const int* __restrict__ mask,
                                                unsigned short* __restrict__ Ac) {
    __shared__ unsigned short Ks[8192];   // [128 key][64 d], 8-slot swz per row
    __shared__ unsigned short Vs[8192];   // [64 d][128 key], 16-slot swz per row
    __shared__ unsigned short Pb[8][16 * 32];   // fp16 P, chunk-XOR swizzled

    const int tid  = threadIdx.x;
    const int lane = tid & 63;
    const int wid  = tid >> 6;

    const int bid = blockIdx.x;
    const int swz = (bid & 7) * 128 + (bid >> 3);
    const int qt  = swz & 15;
    const int bh  = swz >> 4;
    const int b   = bh >> 4;
    const int h   = bh & 15;

    const int q0  = qt * 128;
    const int wq0 = wid * 16;

    const int fr = lane & 15;
    const int fg = lane >> 4;

    const unsigned short* qb   = Q16 + ((size_t)bh * SS + q0 + wq0) * DK;
    const unsigned short* kb16 = K16 + (size_t)bh * SS * DK;
    const unsigned short* vb16 = VT16 + (size_t)bh * DK * SS;
    const int* mrow = mask + b * SS;

    // Q fragments: direct fp16 loads (already scaled)
    f16x8 qf[2];
#pragma unroll
    for (int kb = 0; kb < 2; ++kb)
        qf[kb] = *(const f16x8*)&qb[(size_t)fr * DK + kb * 32 + fg * 8];

    f16x8 ONES16;
#pragma unroll
    for (int i = 0; i < 8; ++i) ONES16[i] = (_Float16)1.0f;

    f32x4 O[4] = {};
    f32x4 Lacc = {};

    // staging: 1024 chunks per array, 2 per thread per array
    const int c0 = tid, c1 = tid + 512;
    const int k0r = c0 >> 3, k0s = c0 & 7;
    const int k1r = c1 >> 3, k1s = c1 & 7;
    const int k0d = k0r * 64 + ((k0s ^ (k0r & 7)) << 3);
    const int k1d = k1r * 64 + ((k1s ^ (k1r & 7)) << 3);
    const int k0g = k0r * 64 + k0s * 8;      // + kv0*64
    const int k1g = k1r * 64 + k1s * 8;
    const int v0r = c0 >> 4, v0s = c0 & 15;
    const int v1r = c1 >> 4, v1s = c1 & 15;
    const int v0d = v0r * 128 + ((v0s ^ (v0r & 15)) << 3);
    const int v1d = v1r * 128 + ((v1s ^ (v1r & 15)) << 3);
    const int v0g = v0r * SS + v0s * 8;      // + kv0
    const int v1g = v1r * SS + v1s * 8;

    const int sl0 = ((0 + fg) ^ (fr & 7)) * 8;
    const int sl1 = ((4 + fg) ^ (fr & 7)) * 8;

    unsigned short* pw16 = Pb[wid];
    // P read: single 16B chunk, logical chunk fg, swizzled by row(fr)&3
    const int prd_off = fr * 32 + ((fg ^ (fr & 3)) << 3);

    // prologue: stage tile 0 into regs
    u16x8 rK0 = *(const u16x8*)&kb16[k0g];
    u16x8 rK1 = *(const u16x8*)&kb16[k1g];
    u16x8 rV0 = *(const u16x8*)&vb16[v0g];
    u16x8 rV1 = *(const u16x8*)&vb16[v1g];

    for (int t = 0; t < SS / 128; ++t) {
        const int kv0 = t * 128;

        __syncthreads();   // previous tile's LDS reads complete
        *(u16x8*)&Ks[k0d] = rK0;
        *(u16x8*)&Ks[k1d] = rK1;
        *(u16x8*)&Vs[v0d] = rV0;
        *(u16x8*)&Vs[v1d] = rV1;
        __syncthreads();   // tile t visible

        if (t + 1 < SS / 128) {
            const int kn = kv0 + 128;
            rK0 = *(const u16x8*)&kb16[(size_t)kn * 64 + k0g];
            rK1 = *(const u16x8*)&kb16[(size_t)kn * 64 + k1g];
            rV0 = *(const u16x8*)&vb16[v0g + kn];
            rV1 = *(const u16x8*)&vb16[v1g + kn];
        }

        // two 64-key sub-tiles
#pragma unroll
        for (int sub = 0; sub < 2; ++sub) {
            const int kvs = kv0 + sub * 64;

            int mv[4];
#pragma unroll
            for (int kyb = 0; kyb < 4; ++kyb) mv[kyb] = mrow[kvs + kyb * 16 + fr];

            // --- QK^T: 8 MFMA
            f32x4 acc[4] = {};
            __builtin_amdgcn_s_setprio(1);
#pragma unroll
            for (int kyb = 0; kyb < 4; ++kyb) {
                const int rb = (sub * 64 + kyb * 16 + fr) * 64;
                f16x8 k0 = *(const f16x8*)&Ks[rb + sl0];
                f16x8 k1 = *(const f16x8*)&Ks[rb + sl1];
                acc[kyb] = __builtin_amdgcn_mfma_f32_16x16x32_f16(qf[0], k0, acc[kyb], 0, 0, 0);
                acc[kyb] = __builtin_amdgcn_mfma_f32_16x16x32_f16(qf[1], k1, acc[kyb], 0, 0, 0);
            }
            __builtin_amdgcn_s_setprio(0);

            // --- two PV half-phases; fixed-max softmax fused into P-write
#pragma unroll
            for (int ph2 = 0; ph2 < 2; ++ph2) {
#pragma unroll
                for (int kyb2 = 0; kyb2 < 2; ++kyb2) {
                    const int kyb = ph2 * 2 + kyb2;
#pragma unroll
                    for (int r = 0; r < 4; ++r) {
                        int row = fg * 4 + r;
                        int co  = kyb2 * 16 + fr;
                        int ch  = (co >> 3) ^ (row & 3);
                        float pv = mv[kyb] ? EXP2(acc[kyb][r]) : 0.f;
                        pw16[row * 32 + ch * 8 + (co & 7)] = f2h(pv);
                    }
                }

                asm volatile("s_waitcnt lgkmcnt(0)" ::: "memory");
                __builtin_amdgcn_sched_barrier(0);

                f16x8 pf = *(const f16x8*)&pw16[prd_off];

                // V logical key-chunk: sub*8 + ph2*4 + fg, swizzled by row&15=fr
                const int vsl = (((sub * 8 + ph2 * 4 + fg) ^ (fr & 15)) << 3);
                __builtin_amdgcn_s_setprio(1);
                Lacc = __builtin_amdgcn_mfma_f32_16x16x32_f16(pf, ONES16, Lacc, 0, 0, 0);
#pragma unroll
                for (int db = 0; db < 4; ++db) {
                    const int rb = (db * 16 + fr) * 128 + vsl;
                    f16x8 vf = *(const f16x8*)&Vs[rb];
                    O[db] = __builtin_amdgcn_mfma_f32_16x16x32_f16(pf, vf, O[db], 0, 0, 0);
                }
                __builtin_amdgcn_s_setprio(0);

                // WAR fence: Pbuf reads retired before next writes
                asm volatile("s_waitcnt lgkmcnt(0)" ::: "memory");
                __builtin_amdgcn_sched_barrier(0);
            }
        }
    }

    // --- epilogue: fp16 tiled-swizzled ctx store
#pragma unroll
    for (int r = 0; r < 4; ++r) {
        float inv = 1.0f / Lacc[r];
        int m  = b * SS + q0 + wq0 + fg * 4 + r;
        int rt = m & 127;
        int mt = m >> 7;
        int rx = (rt & 3) ^ ((rt >> 2) & 3);
#pragma unroll
        for (int db = 0; db < 4; ++db) {
            float val = O[db][r] * inv;
            int kcol = h * 64 + db * 16 + fr;
            int tile = mt * 32 + (kcol >> 5);
            int slot = (((kcol >> 3) & 3)) ^ rx;
            size_t doff = (size_t)tile * 4096 + rt * 32 + slot * 8 + (kcol & 7);
            Ac[doff] = f2h(val);
        }
    }
}

// ---------------------------------------------------------------------------
// fp32 GEMM + old attention (fallback path, unchanged/validated)
// ---------------------------------------------------------------------------
template <int MODE>
__global__ __launch_bounds__(256) void gemm_xwT(const float* __restrict__ A,
                                                const float* __restrict__ W,
                                                const float* __restrict__ bias,
                                                float* __restrict__ C,
                                                unsigned short* __restrict__ Chi,
                                                unsigned short* __restrict__ Clo,
                                                int M, int N, int K) {
    __shared__ float As[8][132];
    __shared__ float Bs[8][132];

    const int tid = threadIdx.x;
    const int tx  = tid & 15;
    const int ty  = tid >> 4;
    const int m0  = blockIdx.y * 128;
    const int n0  = blockIdx.x * 128;

    const int lr = tid >> 1;
    const int lk = (tid & 1) * 4;

    float acc[8][8];
#pragma unroll
    for (int i = 0; i < 8; ++i)
#pragma unroll
        for (int j = 0; j < 8; ++j) acc[i][j] = 0.f;

    for (int kt = 0; kt < K; kt += 8) {
        float4 av = *(const float4*)&A[(size_t)(m0 + lr) * K + kt + lk];
        float4 wv = *(const float4*)&W[(size_t)(n0 + lr) * K + kt + lk];
        __syncthreads();
        As[lk + 0][lr] = av.x; As[lk + 1][lr] = av.y;
        As[lk + 2][lr] = av.z; As[lk + 3][lr] = av.w;
        Bs[lk + 0][lr] = wv.x; Bs[lk + 1][lr] = wv.y;
        Bs[lk + 2][lr] = wv.z; Bs[lk + 3][lr] = wv.w;
        __syncthreads();
#pragma unroll
        for (int k = 0; k < 8; ++k) {
            float4 a0 = *(const float4*)&As[k][ty * 8];
            float4 a1 = *(const float4*)&As[k][ty * 8 + 4];
            float4 b0 = *(const float4*)&Bs[k][tx * 8];
            float4 b1 = *(const float4*)&Bs[k][tx * 8 + 4];
            float a[8] = {a0.x, a0.y, a0.z, a0.w, a1.x, a1.y, a1.z, a1.w};
            float b[8] = {b0.x, b0.y, b0.z, b0.w, b1.x, b1.y, b1.z, b1.w};
#pragma unroll
            for (int i = 0; i < 8; ++i)
#pragma unroll
                for (int j = 0; j < 8; ++j) acc[i][j] += a[i] * b[j];
        }
    }

    float bb[8];
#pragma unroll
    for (int j = 0; j < 8; ++j) bb[j] = bias[n0 + tx * 8 + j];

#pragma unroll
    for (int i = 0; i < 8; ++i) {
        int m = m0 + ty * 8 + i;
        int n = n0 + tx * 8;
        float cv[8];
#pragma unroll
        for (int j = 0; j < 8; ++j) cv[j] = acc[i][j] + bb[j];

        if (MODE == 0) {
            float* dst = &C[(size_t)m * N + n];
            *(float4*)&dst[0] = {cv[0], cv[1], cv[2], cv[3]};
            *(float4*)&dst[4] = {cv[4], cv[5], cv[6], cv[7]};
        } else {
            int bq = m >> 11;
            int s  = m & (SS - 1);
            int h  = n >> 6;
            int d  = n & 63;
            size_t base = (((size_t)(bq * NHEAD + h) * SS + s) << 6) + d;
            if (MODE == 1) {
                float* dst = &C[base];
                *(float4*)&dst[0] = {cv[0], cv[1], cv[2], cv[3]};
                *(float4*)&dst[4] = {cv[4], cv[5], cv[6], cv[7]};
            } else {
                u16x8 h8, l8;
#pragma unroll
                for (int j = 0; j < 8; ++j) {
                    unsigned short hv = f2bf(cv[j]);
                    h8[j] = hv;
                    l8[j] = f2bf(cv[j] - bf2f(hv));
                }
                *(u16x8*)&Chi[base] = h8;
                *(u16x8*)&Clo[base] = l8;
            }
        }
    }
}

__global__ __launch_bounds__(256) void attn_mfma(const float* __restrict__ Qp,
                                                 const unsigned short* __restrict__ Khig,
                                                 const unsigned short* __restrict__ Klog,
                                                 const unsigned short* __restrict__ Vhig,
                                                 const unsigned short* __restrict__ Vlog,
                                                 const int* __restrict__ mask,
                                                 float* __restrict__ ctx) {
    __shared__ short Khi[32 * 72], Klo[32 * 72];
    __shared__ short Vhi[64 * 40], Vlo[64 * 40];
    __shared__ float Pbuf[4][16 * 36];
    __shared__ int   msk[32];

    const int tid  = threadIdx.x;
    const int lane = tid & 63;
    const int wid  = tid >> 6;

    const int bid = blockIdx.x;
    const int swz = (bid & 7) * 256 + (bid >> 3);
    const int qt  = swz & 31;
    const int bh  = swz >> 5;
    const int b   = bh >> 4;
    const int h   = bh & 15;

    const int q0  = qt * 64;
    const int wq0 = wid * 16;

    const int fr = lane & 15;
    const int fg = lane >> 4;

    const float* qbase = Qp + ((size_t)bh * SS + q0 + wq0) * DK;
    const unsigned short* khbase = Khig + (size_t)bh * SS * DK;
    const unsigned short* klbase = Klog + (size_t)bh * SS * DK;
    const unsigned short* vhbase = Vhig + (size_t)bh * SS * DK;
    const unsigned short* vlbase = Vlog + (size_t)bh * SS * DK;
    const int* mrow = mask + b * SS;

    bf16x8 qh[2], ql[2];
#pragma unroll
    for (int kb = 0; kb < 2; ++kb) {
        const float* p = qbase + (size_t)fr * DK + kb * 32 + fg * 8;
        float4 a  = *(const float4*)p;
        float4 b4 = *(const float4*)(p + 4);
        float vals[8] = {a.x, a.y, a.z, a.w, b4.x, b4.y, b4.z, b4.w};
#pragma unroll
        for (int i = 0; i < 8; ++i) {
            float s = vals[i] * 0.125f;
            unsigned short hi = f2bf(s);
            qh[kb][i] = (short)hi;
            ql[kb][i] = (short)f2bf(s - bf2f(hi));
        }
    }

    f32x4 O[4] = {};
    float m_run[4], l_run[4];
#pragma unroll
    for (int r = 0; r < 4; ++r) { m_run[r] = -3.0e38f; l_run[r] = 0.f; }

    const int sk_k = tid >> 3;
    const int sk_d = (tid & 7) * 8;
    const int sv_d = tid & 63;
    const int sv_k = (tid >> 6) * 8;

    for (int t = 0; t < SS / 32; ++t) {
        const int kv0 = t * 32;

        size_t koff = (size_t)(kv0 + sk_k) * DK + sk_d;
        u16x8 kh8 = *(const u16x8*)&khbase[koff];
        u16x8 kl8 = *(const u16x8*)&klbase[koff];
        unsigned short vh[8], vl[8];
#pragma unroll
        for (int j = 0; j < 8; ++j) {
            size_t voff = (size_t)(kv0 + sv_k + j) * DK + sv_d;
            vh[j] = vhbase[voff];
            vl[j] = vlbase[voff];
        }
        int mval = (tid < 32) ? mrow[kv0 + tid] : 0;

        __syncthreads();
        *(u16x8*)&Khi[sk_k * 72 + sk_d] = kh8;
        *(u16x8*)&Klo[sk_k * 72 + sk_d] = kl8;
        {
            u16x8 h8, l8;
#pragma unroll
            for (int j = 0; j < 8; ++j) { h8[j] = vh[j]; l8[j] = vl[j]; }
            *(u16x8*)&Vhi[sv_d * 40 + sv_k] = h8;
            *(u16x8*)&Vlo[sv_d * 40 + sv_k] = l8;
        }
        if (tid < 32) msk[tid] = mval;
        __syncthreads();

        f32x4 acc[2] = {};
#pragma unroll
        for (int kyb = 0; kyb < 2; ++kyb) {
#pragma unroll
            for (int kb = 0; kb < 2; ++kb) {
                int idx = (kyb * 16 + fr) * 72 + kb * 32 + fg * 8;
                bf16x8 kh = *(const bf16x8*)&Khi[idx];
                bf16x8 kl = *(const bf16x8*)&Klo[idx];
                acc[kyb] = __builtin_amdgcn_mfma_f32_16x16x32_bf16(qh[kb], kh, acc[kyb], 0, 0, 0);
                acc[kyb] = __builtin_amdgcn_mfma_f32_16x16x32_bf16(qh[kb], kl, acc[kyb], 0, 0, 0);
                acc[kyb] = __builtin_amdgcn_mfma_f32_16x16x32_bf16(ql[kb], kh, acc[kyb], 0, 0, 0);
            }
        }

        float sc[2][4];
#pragma unroll
        for (int kyb = 0; kyb < 2; ++kyb) {
            int mv = msk[kyb * 16 + fr];
#pragma unroll
            for (int r = 0; r < 4; ++r)
                sc[kyb][r] = mv ? acc[kyb][r] : -1.0e9f;
        }
        float scale[4], p[2][4];
#pragma unroll
        for (int r = 0; r < 4; ++r) {
            float v = fmaxf(sc[0][r], sc[1][r]);
            v = fmaxf(v, __shfl_xor(v, 1));
            v = fmaxf(v, __shfl_xor(v, 2));
            v = fmaxf(v, __shfl_xor(v, 4));
            v = fmaxf(v, __shfl_xor(v, 8));
            float m_new = fmaxf(m_run[r], v);
            scale[r] = __expf(m_run[r] - m_new);
            m_run[r] = m_new;
            p[0][r] = __expf(sc[0][r] - m_new);
            p[1][r] = __expf(sc[1][r] - m_new);
            float s = p[0][r] + p[1][r];
            s += __shfl_xor(s, 1);
            s += __shfl_xor(s, 2);
            s += __shfl_xor(s, 4);
            s += __shfl_xor(s, 8);
            l_run[r] = l_run[r] * scale[r] + s;
        }

        float* pw = Pbuf[wid];
#pragma unroll
        for (int r = 0; r < 4; ++r) {
            pw[(fg * 4 + r) * 36 + fr]      = p[0][r];
            pw[(fg * 4 + r) * 36 + 16 + fr] = p[1][r];
        }
#pragma unroll
        for (int db = 0; db < 4; ++db)
#pragma unroll
            for (int r = 0; r < 4; ++r)
                O[db][r] *= scale[r];

        __syncthreads();

        float pr[8];
        {
            const float* prd = &pw[fr * 36 + fg * 8];
            *(float4*)&pr[0] = *(const float4*)&prd[0];
            *(float4*)&pr[4] = *(const float4*)&prd[4];
        }
        bf16x8 ph8, pl8;
#pragma unroll
        for (int i = 0; i < 8; ++i) {
            unsigned short hi = f2bf(pr[i]);
            ph8[i] = (short)hi;
            pl8[i] = (short)f2bf(pr[i] - bf2f(hi));
        }

#pragma unroll
        for (int db = 0; db < 4; ++db) {
            int idx = (db * 16 + fr) * 40 + fg * 8;
            bf16x8 vh8 = *(const bf16x8*)&Vhi[idx];
            bf16x8 vl8 = *(const bf16x8*)&Vlo[idx];
            O[db] = __builtin_amdgcn_mfma_f32_16x16x32_bf16(ph8, vh8, O[db], 0, 0, 0);
            O[db] = __builtin_amdgcn_mfma_f32_16x16x32_bf16(ph8, vl8, O[db], 0, 0, 0);
            O[db] = __builtin_amdgcn_mfma_f32_16x16x32_bf16(pl8, vh8, O[db], 0, 0, 0);
        }
    }

    float* cbase = ctx + ((size_t)b * SS + q0 + wq0) * D_MODEL + h * DK;
#pragma unroll
    for (int r = 0; r < 4; ++r) {
        float inv = 1.0f / l_run[r];
        int q = fg * 4 + r;
#pragma unroll
        for (int db = 0; db < 4; ++db)
            cbase[(size_t)q * D_MODEL + db * 16 + fr] = O[db][r] * inv;
    }
}

// ---------------------------------------------------------------------------
extern "C" void kernel_launch(void* const* d_in, const int* in_sizes, int n_in,
                              void* d_out, int out_size, void* d_ws, size_t ws_size,
                              hipStream_t stream) {
    const float* q    = (const float*)d_in[0];
    const float* k    = (const float*)d_in[1];
    const float* v    = (const float*)d_in[2];
    const int*   mask = (const int*)d_in[3];
    const float* w_q  = (const float*)d_in[4];
    const float* b_q  = (const float*)d_in[5];
    const float* w_k  = (const float*)d_in[6];
    const float* b_k  = (const float*)d_in[7];
    const float* w_v  = (const float*)d_in[8];
    const float* b_v  = (const float*)d_in[9];
    const float* w_o  = (const float*)d_in[10];
    const float* b_o  = (const float*)d_in[11];
    float* out = (float*)d_out;

    const int M = BB * SS;
    const size_t PSZ = (size_t)M * D_MODEL;
    const size_t NEED = (size_t)208 << 20;
    char* w = (char*)d_ws;
    dim3 block(256);

    if (ws_size >= NEED) {
        unsigned short* qp16 = (unsigned short*)(w);                       // fp16 Q, scaled
        unsigned short* k16  = (unsigned short*)(w + ((size_t)16 << 20));  // fp16 K
        unsigned short* vt16 = (unsigned short*)(w + ((size_t)32 << 20));  // fp16 V^T
        unsigned short* Aq   = (unsigned short*)(w + ((size_t)48 << 20));  // fp16 inputs
        unsigned short* Ak   = (unsigned short*)(w + ((size_t)64 << 20));
        unsigned short* Av   = (unsigned short*)(w + ((size_t)80 << 20));
        unsigned short* Wq   = (unsigned short*)(w + ((size_t)96 << 20));  // fp16 weights
        unsigned short* Wk   = (unsigned short*)(w + ((size_t)98 << 20));
        unsigned short* Wv   = (unsigned short*)(w + ((size_t)100 << 20));
        unsigned short* Wo   = (unsigned short*)(w + ((size_t)102 << 20));
        unsigned short* Ac   = Ak;   // fp16 ctx (Ak dead after K-GEMM)

        const int ACT_CHUNKS = M * 128;
        const int W_CHUNKS   = 1024 * 128;

        SplitJobs8 J{};
        J.j[0] = {q,   Aq, ACT_CHUNKS};
        J.j[1] = {k,   Ak, ACT_CHUNKS};
        J.j[2] = {v,   Av, ACT_CHUNKS};
        J.j[3] = {w_q, Wq, W_CHUNKS};
        J.j[4] = {w_k, Wk, W_CHUNKS};
        J.j[5] = {w_v, Wv, W_CHUNKS};
        J.j[6] = {w_o, Wo, W_CHUNKS};
        presplit<<<dim3(4096, 7), block, 0, stream>>>(J);

        dim3 ggrid3(D_MODEL / 128, M / 128, 3);   // fused Q/K/V: 1536 blocks
        gemm_qkv<<<ggrid3, block, 0, stream>>>(Aq, Ak, Av, Wq, Wk, Wv,
                                               b_q, b_k, b_v, qp16, k16, vt16);

        attn_f16<<<dim3(BB * NHEAD * (SS / 128)), dim3(512), 0, stream>>>(
            qp16, k16, vt16, mask, Ac);

        dim3 ggrid(D_MODEL / 128, M / 128);
        gemm_wo<<<ggrid, block, 0, stream>>>(Ac, Wo, b_o, out);
    } else {
        float* qp           = (float*)d_ws;
        unsigned short* khi = (unsigned short*)(qp + PSZ);
        unsigned short* klo = khi + PSZ;
        unsigned short* vhi = klo + PSZ;
        unsigned short* vlo = vhi + PSZ;
        float* ctx          = (float*)(vlo + PSZ);

        dim3 grid(D_MODEL / 128, M / 128);
        gemm_xwT<1><<<grid, block, 0, stream>>>(q, w_q, b_q, qp, nullptr, nullptr, M, D_MODEL, D_MODEL);
        gemm_xwT<2><<<grid, block, 0, stream>>>(k, w_k, b_k, nullptr, khi, klo, M, D_MODEL, D_MODEL);
        gemm_xwT<2><<<grid, block, 0, stream>>>(v, w_v, b_v, nullptr, vhi, vlo, M, D_MODEL, D_MODEL);
        attn_mfma<<<dim3(BB * NHEAD * (SS / 64)), block, 0, stream>>>(qp, khi, klo, vhi, vlo, mask, ctx);
        gemm_xwT<0><<<grid, block, 0, stream>>>(ctx, w_o, b_o, out, nullptr, nullptr, M, D_MODEL, D_MODEL);
    }
}